// Round 1
// baseline (5813.429 us; speedup 1.0000x reference)
//
#include <hip/hip_runtime.h>

// ---------------- problem constants ----------------
#define D_    2048
#define S_    1024
#define H_    32
#define HKV_  16
#define HD_   64
#define E_    32
#define R_    32
#define FF_   8192

// ---------------- workspace layout (floats) ----------------
constexpr size_t MEG = 1u << 20;
constexpr size_t OFF_XN = 0;          // 2M  (also reused as xn2 = rms(h1))
constexpr size_t OFF_QF = 2 * MEG;    // 2M  q pre-rope (s, 2048)
constexpr size_t OFF_KF = 4 * MEG;    // 1M  k pre-rope (s, 1024)
constexpr size_t OFF_QH = 5 * MEG;    // 2M  q (h, s, d)
constexpr size_t OFF_KH = 7 * MEG;    // 1M  k (h, s, d)
constexpr size_t OFF_V  = 8 * MEG;    // 1M  v (h, s, d)
constexpr size_t OFF_O  = 9 * MEG;    // 2M  attn out (s, 2048)
constexpr size_t OFF_H1 = 11 * MEG;   // 2M
constexpr size_t OFF_M  = 2 * MEG;    // 8M  MLP mid — overlays QF..O[first 1M] (dead by then)
constexpr size_t OFF_SM = 13 * MEG;   // small buffers:
constexpr size_t OFF_MU   = OFF_SM;           // 8192
constexpr size_t OFF_T    = OFF_SM + 8192;    // 32
constexpr size_t OFF_GQ   = OFF_SM + 8224;    // 2048
constexpr size_t OFF_GK   = OFF_SM + 10272;   // 1024
constexpr size_t OFF_GO   = OFF_SM + 11296;   // 2048
constexpr size_t OFF_G1   = OFF_SM + 13344;   // 8192
constexpr size_t OFF_G2   = OFF_SM + 21536;   // 2048
constexpr size_t OFF_WTOP = OFF_SM + 23584;   // 1024
constexpr size_t OFF_CNT  = OFF_SM + 24608;   // 32 ints
constexpr size_t OFF_LIST = OFF_SM + 24640;   // 32*1024 ints

__device__ __forceinline__ float ternf(float w) {
    // jnp.clip(jnp.round(w/0.5), -1, 1); jnp.round is half-to-even == rintf
    float r = rintf(w + w);
    return fmaxf(-1.f, fminf(1.f, r));
}

// ---------------- RMSNorm (row-wise) ----------------
__global__ void rms_kernel(const float* __restrict__ x, float* __restrict__ y, int ncols) {
    int row = blockIdx.x;
    const float* xr = x + (size_t)row * ncols;
    float ss = 0.f;
    for (int i = threadIdx.x; i < ncols; i += 256) { float v = xr[i]; ss += v * v; }
    __shared__ float red[256];
    red[threadIdx.x] = ss; __syncthreads();
    for (int s = 128; s > 0; s >>= 1) {
        if (threadIdx.x < s) red[threadIdx.x] += red[threadIdx.x + s];
        __syncthreads();
    }
    float scale = rsqrtf(red[0] / (float)ncols + 1e-6f);
    float* yr = y + (size_t)row * ncols;
    for (int i = threadIdx.x; i < ncols; i += 256) yr[i] = xr[i] * scale;
}

// ---------------- column mean over rows ----------------
__global__ void colmean_kernel(const float* __restrict__ X, float* __restrict__ mu, int M, int N) {
    int c = blockIdx.x * 256 + threadIdx.x;
    if (c >= N) return;
    float s = 0.f;
    for (int r = 0; r < M; ++r) s += X[(size_t)r * N + c];
    mu[c] = s / (float)M;
}

// ---------------- t = Bmat(R x K) @ mu ----------------
__global__ void bmu_kernel(const float* __restrict__ Bm, const float* __restrict__ mu,
                           float* __restrict__ t, int K) {
    int lane = threadIdx.x & 63, wave = threadIdx.x >> 6;
    for (int r = wave; r < R_; r += 4) {
        float s = 0.f;
        const float* br = Bm + (size_t)r * K;
        for (int k = lane; k < K; k += 64) s += br[k] * mu[k];
        for (int off = 32; off > 0; off >>= 1) s += __shfl_down(s, off);
        if (lane == 0) t[r] = s;
    }
}

// ---------------- g[o] = scale[o] + A[o,:] . t ----------------
__global__ void gate_kernel(const float* __restrict__ A, const float* __restrict__ t,
                            const float* __restrict__ scale, float* __restrict__ g, int N) {
    int o = blockIdx.x * 256 + threadIdx.x;
    if (o >= N) return;
    float s = 0.f;
#pragma unroll
    for (int r = 0; r < R_; ++r) s += A[(size_t)o * R_ + r] * t[r];
    g[o] = scale[o] + s;
}

// ---------------- ternary GEMM: C[M,N] = g[n] * (X[M,K] . tern(W[N,K])^T) ----------------
// MODE 0: plain   MODE 1: + resid[M,N]   MODE 2: relu^2
#define BM 64
#define BN 64
#define BK 32
template<int MODE>
__global__ __launch_bounds__(256) void gemm_tern(
        const float* __restrict__ X, const float* __restrict__ W,
        const float* __restrict__ g, const float* __restrict__ resid,
        float* __restrict__ C, int M, int N, int K) {
    __shared__ float Xs[BK][BM + 1];
    __shared__ float Ws[BK][BN + 1];
    int tid = threadIdx.x;
    int tx = tid & 15, ty = tid >> 4;
    int n0 = blockIdx.x * BN, m0 = blockIdx.y * BM;
    float acc[4][4] = {};
    for (int k0 = 0; k0 < K; k0 += BK) {
#pragma unroll
        for (int p = 0; p < 8; ++p) {
            int idx = tid + p * 256;
            int r = idx >> 5, c = idx & 31;
            Xs[c][r] = X[(size_t)(m0 + r) * K + k0 + c];
        }
#pragma unroll
        for (int p = 0; p < 8; ++p) {
            int idx = tid + p * 256;
            int r = idx >> 5, c = idx & 31;
            Ws[c][r] = ternf(W[(size_t)(n0 + r) * K + k0 + c]);
        }
        __syncthreads();
#pragma unroll
        for (int kk = 0; kk < BK; ++kk) {
            float a[4], b[4];
#pragma unroll
            for (int i = 0; i < 4; ++i) a[i] = Xs[kk][ty * 4 + i];
#pragma unroll
            for (int j = 0; j < 4; ++j) b[j] = Ws[kk][tx * 4 + j];
#pragma unroll
            for (int i = 0; i < 4; ++i)
#pragma unroll
                for (int j = 0; j < 4; ++j)
                    acc[i][j] += a[i] * b[j];
        }
        __syncthreads();
    }
#pragma unroll
    for (int i = 0; i < 4; ++i) {
        int m = m0 + ty * 4 + i;
#pragma unroll
        for (int j = 0; j < 4; ++j) {
            int n = n0 + tx * 4 + j;
            float y = acc[i][j] * g[n];
            if (MODE == 1) y += resid[(size_t)m * N + n];
            if (MODE == 2) { float r = fmaxf(y, 0.f); y = r * r; }
            C[(size_t)m * N + n] = y;
        }
    }
}

// ---------------- router: softmax top-1 + expert token lists ----------------
__global__ void router_kernel(const float* __restrict__ xn, const float* __restrict__ rw,
                              float* __restrict__ wtop, int* __restrict__ cnt,
                              int* __restrict__ list) {
    int t = blockIdx.x;
    const float* xr = xn + (size_t)t * D_;
    __shared__ float logits[E_];
    int lane = threadIdx.x & 63, wave = threadIdx.x >> 6;
    for (int e = wave; e < E_; e += 4) {
        float s = 0.f;
        const float* wr = rw + (size_t)e * D_;
        for (int k = lane; k < D_; k += 64) s += xr[k] * wr[k];
        for (int off = 32; off > 0; off >>= 1) s += __shfl_down(s, off);
        if (lane == 0) logits[e] = s;
    }
    __syncthreads();
    if (threadIdx.x == 0) {
        float mx = logits[0]; int mi = 0;
        for (int e = 1; e < E_; ++e) if (logits[e] > mx) { mx = logits[e]; mi = e; }
        float sum = 0.f;
        for (int e = 0; e < E_; ++e) sum += expf(logits[e] - mx);
        wtop[t] = 1.f / sum;             // == max prob
        int pos = atomicAdd(&cnt[mi], 1);
        list[mi * S_ + pos] = t;
    }
}

// ---------------- value MoE: grouped masked ternary GEMV ----------------
// block = (expert e, 16-output tile). Masked int8 weights staged in LDS once.
__global__ __launch_bounds__(256) void moe_kernel(
        const float* __restrict__ xn, const float* __restrict__ wv,
        const float* __restrict__ sv, const float* __restrict__ masks,
        const float* __restrict__ wtop, const int* __restrict__ cnt,
        const int* __restrict__ list, float* __restrict__ vout) {
    int e = blockIdx.x;
    int o0 = blockIdx.y * 16;
    __shared__ char wqs[16 * 2048];   // 32 KB
    __shared__ float xs[2048];        // 8 KB
    int tid = threadIdx.x;
    const float* mbase = masks + (size_t)e * 1024 * 2048;
#pragma unroll
    for (int p = 0; p < 32; ++p) {
        int i = tid + p * 256;        // char4 index in [0, 8192)
        int o = i >> 9;
        int d = (i & 511) << 2;
        const float4 w4 = *(const float4*)(wv + (size_t)(o0 + o) * 2048 + d);
        const float4 m4 = *(const float4*)(mbase + (size_t)(o0 + o) * 2048 + d);
        char4 pk;
        pk.x = (char)(ternf(w4.x) * m4.x);
        pk.y = (char)(ternf(w4.y) * m4.y);
        pk.z = (char)(ternf(w4.z) * m4.z);
        pk.w = (char)(ternf(w4.w) * m4.w);
        *(char4*)&wqs[(size_t)o * 2048 + d] = pk;
    }
    int n = cnt[e];
    int lane = tid & 63, wave = tid >> 6;
    for (int j = 0; j < n; ++j) {
        int t = list[e * S_ + j];
        __syncthreads();   // weights visible (j==0) / prev readers done
        for (int p = tid; p < 512; p += 256)
            *(float4*)&xs[p * 4] = *(const float4*)(xn + (size_t)t * 2048 + p * 4);
        __syncthreads();
        float gate = wtop[t];
#pragma unroll
        for (int i = 0; i < 4; ++i) {
            int o = wave * 4 + i;
            float s = 0.f;
#pragma unroll
            for (int it = 0; it < 8; ++it) {
                int d = it * 256 + lane * 4;
                char4 pk = *(const char4*)&wqs[o * 2048 + d];
                float4 xv = *(const float4*)&xs[d];
                s += xv.x * (float)pk.x + xv.y * (float)pk.y +
                     xv.z * (float)pk.z + xv.w * (float)pk.w;
            }
            for (int off = 32; off > 0; off >>= 1) s += __shfl_down(s, off);
            if (lane == 0) {
                int oo = o0 + o;
                int kvh = oo >> 6, dd = oo & 63;
                vout[((size_t)kvh * S_ + t) * 64 + dd] = gate * sv[oo] * s;
            }
        }
    }
}

// ---------------- RoPE + (s, h*64+d) -> (h, s, d) transpose ----------------
__global__ void rope_kernel(const float* __restrict__ inp, float* __restrict__ outp, int nheads) {
    int i = blockIdx.x * 256 + threadIdx.x;
    int p = i & 31;
    int s = (i >> 5) & 1023;
    int h = i >> 15;
    if (h >= nheads) return;
    int stride = nheads * 64;
    const float* irow = inp + (size_t)s * stride + h * 64;
    float x1 = irow[p], x2 = irow[32 + p];
    // freq = 10000^(-p/32)
    float fr = expf(-(float)p * 0.28782313662425575f);
    float ang = (float)s * fr;
    float sn, cs;
    sincosf(ang, &sn, &cs);
    float* orow = outp + ((size_t)h * S_ + s) * 64;
    orow[p]      = x1 * cs + x2 * sn;
    orow[32 + p] = -x1 * sn + x2 * cs;
}

// ---------------- causal GQA attention, 16 queries per block ----------------
__global__ __launch_bounds__(256) void attn_kernel(
        const float* __restrict__ q, const float* __restrict__ k,
        const float* __restrict__ v, float* __restrict__ o) {
    int h = blockIdx.x;
    int qb = blockIdx.y * 16;
    int kvh = h >> 1;
    const float* kb = k + (size_t)kvh * S_ * 64;
    const float* vb = v + (size_t)kvh * S_ * 64;
    __shared__ float qrow[64];
    __shared__ float probs[S_];
    __shared__ float red[256];
    __shared__ float opart[4][64];
    int tid = threadIdx.x;
    for (int qi = 0; qi < 16; ++qi) {
        int s = qb + qi;
        __syncthreads();
        if (tid < 64) qrow[tid] = q[((size_t)h * S_ + s) * 64 + tid];
        __syncthreads();
        int nk = s + 1;
        float mloc = -1e30f;
        for (int j = tid; j < nk; j += 256) {
            const float4* kr = (const float4*)(kb + (size_t)j * 64);
            float sc = 0.f;
#pragma unroll
            for (int t4 = 0; t4 < 16; ++t4) {
                float4 k4 = kr[t4];
                sc += qrow[t4 * 4] * k4.x + qrow[t4 * 4 + 1] * k4.y +
                      qrow[t4 * 4 + 2] * k4.z + qrow[t4 * 4 + 3] * k4.w;
            }
            sc *= 0.125f;
            probs[j] = sc;
            mloc = fmaxf(mloc, sc);
        }
        red[tid] = mloc; __syncthreads();
        for (int st = 128; st > 0; st >>= 1) {
            if (tid < st) red[tid] = fmaxf(red[tid], red[tid + st]);
            __syncthreads();
        }
        float M = red[0];
        __syncthreads();
        float lloc = 0.f;
        for (int j = tid; j < nk; j += 256) {
            float pv = expf(probs[j] - M);
            probs[j] = pv;
            lloc += pv;
        }
        red[tid] = lloc; __syncthreads();
        for (int st = 128; st > 0; st >>= 1) {
            if (tid < st) red[tid] += red[tid + st];
            __syncthreads();
        }
        float L = red[0];
        int d = tid & 63, quad = tid >> 6;
        float acc = 0.f;
        for (int j = quad; j < nk; j += 4)
            acc += probs[j] * vb[(size_t)j * 64 + d];
        opart[quad][d] = acc;
        __syncthreads();
        if (tid < 64) {
            float sum = opart[0][tid] + opart[1][tid] + opart[2][tid] + opart[3][tid];
            o[(size_t)s * 2048 + h * 64 + tid] = sum / L;
        }
    }
}

// ---------------- launcher ----------------
extern "C" void kernel_launch(void* const* d_in, const int* in_sizes, int n_in,
                              void* d_out, int out_size, void* d_ws, size_t ws_size,
                              hipStream_t stream) {
    const float* x        = (const float*)d_in[0];
    const float* wq       = (const float*)d_in[1];
    const float* sq       = (const float*)d_in[2];
    const float* Aq       = (const float*)d_in[3];
    const float* Bq       = (const float*)d_in[4];
    const float* wk       = (const float*)d_in[5];
    const float* sk       = (const float*)d_in[6];
    const float* Ak       = (const float*)d_in[7];
    const float* Bk       = (const float*)d_in[8];
    const float* wv       = (const float*)d_in[9];
    const float* sv       = (const float*)d_in[10];
    const float* masks    = (const float*)d_in[11];
    const float* router_w = (const float*)d_in[12];
    const float* wo       = (const float*)d_in[13];
    const float* so       = (const float*)d_in[14];
    const float* Ao       = (const float*)d_in[15];
    const float* Bo       = (const float*)d_in[16];
    const float* w1       = (const float*)d_in[17];
    const float* s1       = (const float*)d_in[18];
    const float* A1       = (const float*)d_in[19];
    const float* B1       = (const float*)d_in[20];
    const float* w2       = (const float*)d_in[21];
    const float* s2       = (const float*)d_in[22];
    const float* A2       = (const float*)d_in[23];
    const float* B2       = (const float*)d_in[24];

    float* ws   = (float*)d_ws;
    float* out  = (float*)d_out;
    float* xn   = ws + OFF_XN;
    float* qf   = ws + OFF_QF;
    float* kf   = ws + OFF_KF;
    float* qh   = ws + OFF_QH;
    float* kh   = ws + OFF_KH;
    float* vbuf = ws + OFF_V;
    float* obuf = ws + OFF_O;
    float* h1   = ws + OFF_H1;
    float* mbuf = ws + OFF_M;
    float* mu   = ws + OFF_MU;
    float* tvec = ws + OFF_T;
    float* gq   = ws + OFF_GQ;
    float* gk   = ws + OFF_GK;
    float* go   = ws + OFF_GO;
    float* g1   = ws + OFF_G1;
    float* g2   = ws + OFF_G2;
    float* wtop = ws + OFF_WTOP;
    int*   cnt  = (int*)(ws + OFF_CNT);
    int*   list = (int*)(ws + OFF_LIST);

    hipMemsetAsync(cnt, 0, E_ * sizeof(int), stream);

    // xn = rms(x); column mean for corr terms
    rms_kernel<<<S_, 256, 0, stream>>>(x, xn, D_);
    colmean_kernel<<<D_ / 256, 256, 0, stream>>>(xn, mu, S_, D_);

    // Q projection
    bmu_kernel<<<1, 256, 0, stream>>>(Bq, mu, tvec, D_);
    gate_kernel<<<D_ / 256, 256, 0, stream>>>(Aq, tvec, sq, gq, D_);
    gemm_tern<0><<<dim3(D_ / BN, S_ / BM), 256, 0, stream>>>(xn, wq, gq, nullptr, qf, S_, D_, D_);

    // K projection
    bmu_kernel<<<1, 256, 0, stream>>>(Bk, mu, tvec, D_);
    gate_kernel<<<1024 / 256, 256, 0, stream>>>(Ak, tvec, sk, gk, 1024);
    gemm_tern<0><<<dim3(1024 / BN, S_ / BM), 256, 0, stream>>>(xn, wk, gk, nullptr, kf, S_, 1024, D_);

    // V (MoE)
    router_kernel<<<S_, 256, 0, stream>>>(xn, router_w, wtop, cnt, list);
    moe_kernel<<<dim3(E_, 1024 / 16), 256, 0, stream>>>(xn, wv, sv, masks, wtop, cnt, list, vbuf);

    // RoPE + head transpose
    rope_kernel<<<(H_ * S_ * 32) / 256, 256, 0, stream>>>(qf, qh, H_);
    rope_kernel<<<(HKV_ * S_ * 32) / 256, 256, 0, stream>>>(kf, kh, HKV_);

    // attention
    attn_kernel<<<dim3(H_, S_ / 16), 256, 0, stream>>>(qh, kh, vbuf, obuf);

    // output projection + residual
    colmean_kernel<<<D_ / 256, 256, 0, stream>>>(obuf, mu, S_, D_);
    bmu_kernel<<<1, 256, 0, stream>>>(Bo, mu, tvec, D_);
    gate_kernel<<<D_ / 256, 256, 0, stream>>>(Ao, tvec, so, go, D_);
    gemm_tern<1><<<dim3(D_ / BN, S_ / BM), 256, 0, stream>>>(obuf, wo, go, x, h1, S_, D_, D_);

    // MLP up (relu^2)
    rms_kernel<<<S_, 256, 0, stream>>>(h1, xn, D_);   // xn reused as xn2
    colmean_kernel<<<D_ / 256, 256, 0, stream>>>(xn, mu, S_, D_);
    bmu_kernel<<<1, 256, 0, stream>>>(B1, mu, tvec, D_);
    gate_kernel<<<FF_ / 256, 256, 0, stream>>>(A1, tvec, s1, g1, FF_);
    gemm_tern<2><<<dim3(FF_ / BN, S_ / BM), 256, 0, stream>>>(xn, w1, g1, nullptr, mbuf, S_, FF_, D_);

    // MLP down + residual -> out
    colmean_kernel<<<FF_ / 256, 256, 0, stream>>>(mbuf, mu, S_, FF_);
    bmu_kernel<<<1, 256, 0, stream>>>(B2, mu, tvec, FF_);
    gate_kernel<<<D_ / 256, 256, 0, stream>>>(A2, tvec, s2, g2, D_);
    gemm_tern<1><<<dim3(D_ / BN, S_ / BM), 256, 0, stream>>>(mbuf, w2, g2, h1, out, S_, D_, FF_);
}

// Round 3
// 4073.597 us; speedup vs baseline: 1.4271x; 1.4271x over previous
//
#include <hip/hip_runtime.h>

// ---------------- problem constants ----------------
#define D_    2048
#define S_    1024
#define H_    32
#define HKV_  16
#define HD_   64
#define E_    32
#define R_    32
#define FF_   8192

// ---------------- workspace layout ----------------
constexpr size_t MEG = 1u << 20;
// fp32 region (float offsets)
constexpr size_t OFF_XN = 0;          // 2M
constexpr size_t OFF_QF = 2 * MEG;    // 2M
constexpr size_t OFF_KF = 4 * MEG;    // 1M
constexpr size_t OFF_QH = 5 * MEG;    // 2M
constexpr size_t OFF_KH = 7 * MEG;    // 1M
constexpr size_t OFF_V  = 8 * MEG;    // 1M
constexpr size_t OFF_O  = 9 * MEG;    // 2M
constexpr size_t OFF_H1 = 11 * MEG;   // 2M
constexpr size_t OFF_M  = 2 * MEG;    // 8M MLP mid — overlays QF..O (dead by then)
constexpr size_t OFF_SM = 13 * MEG;
constexpr size_t OFF_MU   = OFF_SM;
constexpr size_t OFF_T    = OFF_SM + 8192;
constexpr size_t OFF_GQ   = OFF_SM + 8224;
constexpr size_t OFF_GK   = OFF_SM + 10272;
constexpr size_t OFF_GO   = OFF_SM + 11296;
constexpr size_t OFF_G1   = OFF_SM + 13344;
constexpr size_t OFF_G2   = OFF_SM + 21536;
constexpr size_t OFF_WTOP = OFF_SM + 23584;
constexpr size_t OFF_CNT  = OFF_SM + 24608;
constexpr size_t OFF_LIST = OFF_SM + 24640;
// bf16 region begins at float offset 14M (ushort offsets from bb)
constexpr size_t FP32_FLOATS = 14 * MEG;
constexpr size_t BOFF_WQ = 0;                    // 4M
constexpr size_t BOFF_WK = 4 * MEG;              // 2M
constexpr size_t BOFF_WO = 6 * MEG;              // 4M
constexpr size_t BOFF_W1 = 10 * MEG;             // 16M
constexpr size_t BOFF_W2 = 26 * MEG;             // 16M
constexpr size_t BOFF_XN = 42 * MEG;             // 2M
constexpr size_t BOFF_OB = 44 * MEG;             // 2M
constexpr size_t BOFF_MB = 46 * MEG;             // 8M
constexpr size_t BF16_USHORTS = 54 * MEG;
constexpr size_t WS_NEED = FP32_FLOATS * 4 + BF16_USHORTS * 2;

typedef __attribute__((ext_vector_type(8))) short bf16x8;
typedef __attribute__((ext_vector_type(4))) float f32x4;

__device__ __forceinline__ float ternf(float w) {
    // clip(round(w/0.5), -1, 1); round half-to-even == rintf
    return __builtin_amdgcn_fmed3f(rintf(w + w), -1.f, 1.f);
}
__device__ __forceinline__ unsigned bfpk2(float a, float b) {
    unsigned ua = __float_as_uint(a), ub = __float_as_uint(b);
    ua = (ua + 0x7fffu + ((ua >> 16) & 1u)) >> 16;
    ub = (ub + 0x7fffu + ((ub >> 16) & 1u)) & 0xffff0000u;
    return ua | ub;
}
// split fp32 pair into (hi, lo) bf16 pairs: a ~= hi + lo to ~2^-17 rel
__device__ __forceinline__ void split_pack(float a, float b, unsigned& hi, unsigned& lo) {
    unsigned ua = __float_as_uint(a), ub = __float_as_uint(b);
    unsigned ha = (ua + 0x7fffu + ((ua >> 16) & 1u)) & 0xffff0000u;
    unsigned hb = (ub + 0x7fffu + ((ub >> 16) & 1u)) & 0xffff0000u;
    hi = (ha >> 16) | hb;
    lo = bfpk2(a - __uint_as_float(ha), b - __uint_as_float(hb));
}

// ---------------- RMSNorm ----------------
__global__ void rms_kernel(const float* __restrict__ x, float* __restrict__ y, int ncols) {
    int row = blockIdx.x;
    const float* xr = x + (size_t)row * ncols;
    float ss = 0.f;
    for (int i = threadIdx.x; i < ncols; i += 256) { float v = xr[i]; ss += v * v; }
    __shared__ float red[256];
    red[threadIdx.x] = ss; __syncthreads();
    for (int s = 128; s > 0; s >>= 1) {
        if (threadIdx.x < s) red[threadIdx.x] += red[threadIdx.x + s];
        __syncthreads();
    }
    float scale = rsqrtf(red[0] / (float)ncols + 1e-6f);
    float* yr = y + (size_t)row * ncols;
    for (int i = threadIdx.x; i < ncols; i += 256) yr[i] = xr[i] * scale;
}

// ---------------- column mean ----------------
__global__ void colmean_kernel(const float* __restrict__ X, float* __restrict__ mu, int M, int N) {
    int c = blockIdx.x * 256 + threadIdx.x;
    if (c >= N) return;
    float s = 0.f;
    for (int r = 0; r < M; ++r) s += X[(size_t)r * N + c];
    mu[c] = s / (float)M;
}

// ---------------- t = B(RxK) @ mu ----------------
__global__ void bmu_kernel(const float* __restrict__ Bm, const float* __restrict__ mu,
                           float* __restrict__ t, int K) {
    int lane = threadIdx.x & 63, wave = threadIdx.x >> 6;
    for (int r = wave; r < R_; r += 4) {
        float s = 0.f;
        const float* br = Bm + (size_t)r * K;
        for (int k = lane; k < K; k += 64) s += br[k] * mu[k];
        for (int off = 32; off > 0; off >>= 1) s += __shfl_down(s, off);
        if (lane == 0) t[r] = s;
    }
}

// ---------------- g[o] = scale[o] + A[o,:] . t ----------------
__global__ void gate_kernel(const float* __restrict__ A, const float* __restrict__ t,
                            const float* __restrict__ scale, float* __restrict__ g, int N) {
    int o = blockIdx.x * 256 + threadIdx.x;
    if (o >= N) return;
    float s = 0.f;
#pragma unroll
    for (int r = 0; r < R_; ++r) s += A[(size_t)o * R_ + r] * t[r];
    g[o] = scale[o] + s;
}

// ---------------- converts ----------------
__global__ void cvtb_kernel(const float* __restrict__ x, unsigned* __restrict__ y, int n4) {
    int i = blockIdx.x * 256 + threadIdx.x;
    if (i >= n4) return;
    float4 v = ((const float4*)x)[i];
    ((uint2*)y)[i] = make_uint2(bfpk2(v.x, v.y), bfpk2(v.z, v.w));
}
__global__ void ternb_kernel(const float* __restrict__ w, unsigned* __restrict__ y, int n4) {
    int i = blockIdx.x * 256 + threadIdx.x;
    if (i >= n4) return;
    float4 v = ((const float4*)w)[i];
    ((uint2*)y)[i] = make_uint2(bfpk2(ternf(v.x), ternf(v.y)),
                                bfpk2(ternf(v.z), ternf(v.w)));
}

// ---------------- single-bf16 MFMA GEMM: C = g[n]*(X . tern(W)^T) ----------------
// Tile 64x128, BK=32, 4 waves 2x2. Used on smooth paths (O-proj, MLP).
template<int MODE, int PRE>
__global__ __launch_bounds__(256) void gemm_mfma(
        const void* __restrict__ Xv, const void* __restrict__ Wv,
        const float* __restrict__ g, const float* __restrict__ resid,
        float* __restrict__ C, int M, int N, int K) {
    __shared__ unsigned short As[64 * 32];
    __shared__ unsigned short Bs[128 * 32];
    int tid = threadIdx.x;
    int lane = tid & 63, wave = tid >> 6;
    int wm = wave & 1, wn = wave >> 1;
    int m0 = blockIdx.y * 64, n0 = blockIdx.x * 128;
    f32x4 acc[2][4];
#pragma unroll
    for (int i = 0; i < 2; ++i)
#pragma unroll
        for (int j = 0; j < 4; ++j) { f32x4 z = {0.f, 0.f, 0.f, 0.f}; acc[i][j] = z; }

    for (int k0 = 0; k0 < K; k0 += 32) {
        if (PRE) {
            const unsigned short* X = (const unsigned short*)Xv;
            const unsigned short* W = (const unsigned short*)Wv;
            {
                int row = tid >> 2, cg = tid & 3;
                *(uint4*)&As[row * 32 + cg * 8] =
                    *(const uint4*)&X[(size_t)(m0 + row) * K + k0 + cg * 8];
            }
#pragma unroll
            for (int it = 0; it < 2; ++it) {
                int idx = tid + it * 256;
                int row = idx >> 2, cg = idx & 3;
                *(uint4*)&Bs[row * 32 + cg * 8] =
                    *(const uint4*)&W[(size_t)(n0 + row) * K + k0 + cg * 8];
            }
        } else {
            const float* X = (const float*)Xv;
            const float* W = (const float*)Wv;
#pragma unroll
            for (int it = 0; it < 2; ++it) {
                int idx = tid + it * 256;
                int row = idx >> 3, cg = idx & 7;
                float4 v = *(const float4*)&X[(size_t)(m0 + row) * K + k0 + cg * 4];
                *(uint2*)&As[row * 32 + cg * 4] =
                    make_uint2(bfpk2(v.x, v.y), bfpk2(v.z, v.w));
            }
#pragma unroll
            for (int it = 0; it < 4; ++it) {
                int idx = tid + it * 256;
                int row = idx >> 3, cg = idx & 7;
                float4 v = *(const float4*)&W[(size_t)(n0 + row) * K + k0 + cg * 4];
                *(uint2*)&Bs[row * 32 + cg * 4] =
                    make_uint2(bfpk2(ternf(v.x), ternf(v.y)),
                               bfpk2(ternf(v.z), ternf(v.w)));
            }
        }
        __syncthreads();
        bf16x8 a[2], b[4];
#pragma unroll
        for (int mi = 0; mi < 2; ++mi)
            a[mi] = *(const bf16x8*)&As[(wm * 32 + mi * 16 + (lane & 15)) * 32 + (lane >> 4) * 8];
#pragma unroll
        for (int ni = 0; ni < 4; ++ni)
            b[ni] = *(const bf16x8*)&Bs[(wn * 64 + ni * 16 + (lane & 15)) * 32 + (lane >> 4) * 8];
#pragma unroll
        for (int mi = 0; mi < 2; ++mi)
#pragma unroll
            for (int ni = 0; ni < 4; ++ni)
                acc[mi][ni] = __builtin_amdgcn_mfma_f32_16x16x32_bf16(
                    a[mi], b[ni], acc[mi][ni], 0, 0, 0);
        __syncthreads();
    }
#pragma unroll
    for (int mi = 0; mi < 2; ++mi) {
        int rowb = m0 + wm * 32 + mi * 16 + (lane >> 4) * 4;
#pragma unroll
        for (int ni = 0; ni < 4; ++ni) {
            int col = n0 + wn * 64 + ni * 16 + (lane & 15);
            float gg = g[col];
#pragma unroll
            for (int rr = 0; rr < 4; ++rr) {
                int row = rowb + rr;
                float y = acc[mi][ni][rr] * gg;
                if (MODE == 1) y += resid[(size_t)row * N + col];
                if (MODE == 2) { float r = fmaxf(y, 0.f); y = r * r; }
                C[(size_t)row * N + col] = y;
            }
        }
    }
}

// ---------------- split-bf16 (double) MFMA GEMM — fp32-grade accuracy ----------------
// X fp32 staged as hi+lo bf16; W ternary (exact in bf16). Used for Q/K (score path:
// softmax is quasi-one-hot, argmax must match fp32 reference).
template<int PREW>
__global__ __launch_bounds__(256) void gemm_mfma_dbl(
        const float* __restrict__ X, const void* __restrict__ Wv,
        const float* __restrict__ g, float* __restrict__ C, int M, int N, int K) {
    __shared__ unsigned short Ah[64 * 32];
    __shared__ unsigned short Al[64 * 32];
    __shared__ unsigned short Bs[128 * 32];
    int tid = threadIdx.x;
    int lane = tid & 63, wave = tid >> 6;
    int wm = wave & 1, wn = wave >> 1;
    int m0 = blockIdx.y * 64, n0 = blockIdx.x * 128;
    f32x4 acc[2][4];
#pragma unroll
    for (int i = 0; i < 2; ++i)
#pragma unroll
        for (int j = 0; j < 4; ++j) { f32x4 z = {0.f, 0.f, 0.f, 0.f}; acc[i][j] = z; }

    for (int k0 = 0; k0 < K; k0 += 32) {
#pragma unroll
        for (int it = 0; it < 2; ++it) {   // A: 512 float4 -> hi/lo
            int idx = tid + it * 256;
            int row = idx >> 3, cg = idx & 7;
            float4 v = *(const float4*)&X[(size_t)(m0 + row) * K + k0 + cg * 4];
            unsigned h0, l0, h1, l1;
            split_pack(v.x, v.y, h0, l0);
            split_pack(v.z, v.w, h1, l1);
            *(uint2*)&Ah[row * 32 + cg * 4] = make_uint2(h0, h1);
            *(uint2*)&Al[row * 32 + cg * 4] = make_uint2(l0, l1);
        }
        if (PREW) {
            const unsigned short* W = (const unsigned short*)Wv;
#pragma unroll
            for (int it = 0; it < 2; ++it) {
                int idx = tid + it * 256;
                int row = idx >> 2, cg = idx & 3;
                *(uint4*)&Bs[row * 32 + cg * 8] =
                    *(const uint4*)&W[(size_t)(n0 + row) * K + k0 + cg * 8];
            }
        } else {
            const float* W = (const float*)Wv;
#pragma unroll
            for (int it = 0; it < 4; ++it) {
                int idx = tid + it * 256;
                int row = idx >> 3, cg = idx & 7;
                float4 v = *(const float4*)&W[(size_t)(n0 + row) * K + k0 + cg * 4];
                *(uint2*)&Bs[row * 32 + cg * 4] =
                    make_uint2(bfpk2(ternf(v.x), ternf(v.y)),
                               bfpk2(ternf(v.z), ternf(v.w)));
            }
        }
        __syncthreads();
        bf16x8 ah[2], al[2], b[4];
#pragma unroll
        for (int mi = 0; mi < 2; ++mi) {
            int off = (wm * 32 + mi * 16 + (lane & 15)) * 32 + (lane >> 4) * 8;
            ah[mi] = *(const bf16x8*)&Ah[off];
            al[mi] = *(const bf16x8*)&Al[off];
        }
#pragma unroll
        for (int ni = 0; ni < 4; ++ni)
            b[ni] = *(const bf16x8*)&Bs[(wn * 64 + ni * 16 + (lane & 15)) * 32 + (lane >> 4) * 8];
#pragma unroll
        for (int mi = 0; mi < 2; ++mi)
#pragma unroll
            for (int ni = 0; ni < 4; ++ni) {
                acc[mi][ni] = __builtin_amdgcn_mfma_f32_16x16x32_bf16(
                    al[mi], b[ni], acc[mi][ni], 0, 0, 0);
                acc[mi][ni] = __builtin_amdgcn_mfma_f32_16x16x32_bf16(
                    ah[mi], b[ni], acc[mi][ni], 0, 0, 0);
            }
        __syncthreads();
    }
#pragma unroll
    for (int mi = 0; mi < 2; ++mi) {
        int rowb = m0 + wm * 32 + mi * 16 + (lane >> 4) * 4;
#pragma unroll
        for (int ni = 0; ni < 4; ++ni) {
            int col = n0 + wn * 64 + ni * 16 + (lane & 15);
            float gg = g[col];
#pragma unroll
            for (int rr = 0; rr < 4; ++rr)
                C[(size_t)(rowb + rr) * N + col] = acc[mi][ni][rr] * gg;
        }
    }
}

// ---------------- router ----------------
__global__ void router_kernel(const float* __restrict__ xn, const float* __restrict__ rw,
                              float* __restrict__ wtop, int* __restrict__ cnt,
                              int* __restrict__ list) {
    int t = blockIdx.x;
    const float* xr = xn + (size_t)t * D_;
    __shared__ float logits[E_];
    int lane = threadIdx.x & 63, wave = threadIdx.x >> 6;
    for (int e = wave; e < E_; e += 4) {
        float s = 0.f;
        const float* wr = rw + (size_t)e * D_;
        for (int k = lane; k < D_; k += 64) s += xr[k] * wr[k];
        for (int off = 32; off > 0; off >>= 1) s += __shfl_down(s, off);
        if (lane == 0) logits[e] = s;
    }
    __syncthreads();
    if (threadIdx.x == 0) {
        float mx = logits[0]; int mi = 0;
        for (int e = 1; e < E_; ++e) if (logits[e] > mx) { mx = logits[e]; mi = e; }
        float sum = 0.f;
        for (int e = 0; e < E_; ++e) sum += expf(logits[e] - mx);
        wtop[t] = 1.f / sum;
        int pos = atomicAdd(&cnt[mi], 1);
        list[mi * S_ + pos] = t;
    }
}

// ---------------- value MoE ----------------
__global__ __launch_bounds__(256) void moe_kernel(
        const float* __restrict__ xn, const float* __restrict__ wv,
        const float* __restrict__ sv, const float* __restrict__ masks,
        const float* __restrict__ wtop, const int* __restrict__ cnt,
        const int* __restrict__ list, float* __restrict__ vout) {
    int e = blockIdx.x;
    int o0 = blockIdx.y * 16;
    __shared__ char wqs[16 * 2048];
    __shared__ float xs[2048];
    int tid = threadIdx.x;
    const float* mbase = masks + (size_t)e * 1024 * 2048;
#pragma unroll
    for (int p = 0; p < 32; ++p) {
        int i = tid + p * 256;
        int o = i >> 9;
        int d = (i & 511) << 2;
        const float4 w4 = *(const float4*)(wv + (size_t)(o0 + o) * 2048 + d);
        const float4 m4 = *(const float4*)(mbase + (size_t)(o0 + o) * 2048 + d);
        char4 pk;
        pk.x = (char)(ternf(w4.x) * m4.x);
        pk.y = (char)(ternf(w4.y) * m4.y);
        pk.z = (char)(ternf(w4.z) * m4.z);
        pk.w = (char)(ternf(w4.w) * m4.w);
        *(char4*)&wqs[(size_t)o * 2048 + d] = pk;
    }
    int n = cnt[e];
    int lane = tid & 63, wave = tid >> 6;
    for (int j = 0; j < n; ++j) {
        int t = list[e * S_ + j];
        __syncthreads();
        for (int p = tid; p < 512; p += 256)
            *(float4*)&xs[p * 4] = *(const float4*)(xn + (size_t)t * 2048 + p * 4);
        __syncthreads();
        float gate = wtop[t];
#pragma unroll
        for (int i = 0; i < 4; ++i) {
            int o = wave * 4 + i;
            float s = 0.f;
#pragma unroll
            for (int it = 0; it < 8; ++it) {
                int d = it * 256 + lane * 4;
                char4 pk = *(const char4*)&wqs[o * 2048 + d];
                float4 xv = *(const float4*)&xs[d];
                s += xv.x * (float)pk.x + xv.y * (float)pk.y +
                     xv.z * (float)pk.z + xv.w * (float)pk.w;
            }
            for (int off = 32; off > 0; off >>= 1) s += __shfl_down(s, off);
            if (lane == 0) {
                int oo = o0 + o;
                int kvh = oo >> 6, dd = oo & 63;
                vout[((size_t)kvh * S_ + t) * 64 + dd] = gate * sv[oo] * s;
            }
        }
    }
}

// ---------------- RoPE + transpose ----------------
__global__ void rope_kernel(const float* __restrict__ inp, float* __restrict__ outp, int nheads) {
    int i = blockIdx.x * 256 + threadIdx.x;
    int p = i & 31;
    int s = (i >> 5) & 1023;
    int h = i >> 15;
    if (h >= nheads) return;
    int stride = nheads * 64;
    const float* irow = inp + (size_t)s * stride + h * 64;
    float x1 = irow[p], x2 = irow[32 + p];
    float fr = expf(-(float)p * 0.28782313662425575f);
    float ang = (float)s * fr;
    float sn, cs;
    sincosf(ang, &sn, &cs);
    float* orow = outp + ((size_t)h * S_ + s) * 64;
    orow[p]      = x1 * cs + x2 * sn;
    orow[32 + p] = -x1 * sn + x2 * cs;
}

// ---------------- attention: 64 queries/block, online softmax ----------------
__global__ __launch_bounds__(256) void attn2_kernel(
        const float* __restrict__ q, const float* __restrict__ k,
        const float* __restrict__ v, float* __restrict__ o) {
    int h = blockIdx.x;
    int qt = gridDim.y - 1 - blockIdx.y;   // heavy blocks first
    int kvh = h >> 1;
    const float* kb = k + (size_t)kvh * S_ * 64;
    const float* vb = v + (size_t)kvh * S_ * 64;
    __shared__ float Ks[64][68];
    __shared__ float Vs[64][68];
    __shared__ float Ss[64][68];
    int tid = threadIdx.x;
    int qi = tid >> 2, p = tid & 3;
    int qg = qt * 64 + qi;
    float4 qr[16];
    const float4* qrow = (const float4*)(q + ((size_t)h * S_ + qg) * 64);
#pragma unroll
    for (int c = 0; c < 16; ++c) qr[c] = qrow[c];
    float4 ov[4];
#pragma unroll
    for (int c = 0; c < 4; ++c) { ov[c].x = 0.f; ov[c].y = 0.f; ov[c].z = 0.f; ov[c].w = 0.f; }
    float mrun = -1e30f, lrun = 0.f;
    int ntile = qt + 1;
    for (int kt = 0; kt < ntile; ++kt) {
        int j0 = kt * 64;
        __syncthreads();
#pragma unroll
        for (int it = 0; it < 4; ++it) {
            int idx = tid + it * 256;
            int row = idx >> 4, c4 = idx & 15;
            *(float4*)&Ks[row][c4 * 4] = *(const float4*)&kb[(size_t)(j0 + row) * 64 + c4 * 4];
            *(float4*)&Vs[row][c4 * 4] = *(const float4*)&vb[(size_t)(j0 + row) * 64 + c4 * 4];
        }
        __syncthreads();
#pragma unroll
        for (int jj = 0; jj < 16; ++jj) {
            int j = p * 16 + jj;
            float s = 0.f;
#pragma unroll
            for (int t4i = 0; t4i < 16; ++t4i) {
                int t4 = (t4i + p * 4) & 15;
                float4 k4 = *(const float4*)&Ks[j][t4 * 4];
                float4 q4 = qr[t4];
                s += q4.x * k4.x + q4.y * k4.y + q4.z * k4.z + q4.w * k4.w;
            }
            int jgl = j0 + j;
            Ss[qi][j] = (jgl <= qg) ? s * 0.125f : -1e30f;
        }
        __syncthreads();
        float tmax = -1e30f;
#pragma unroll
        for (int c = 0; c < 16; ++c) {
            float4 s4 = *(const float4*)&Ss[qi][c * 4];
            tmax = fmaxf(tmax, fmaxf(fmaxf(s4.x, s4.y), fmaxf(s4.z, s4.w)));
        }
        float mnew = fmaxf(mrun, tmax);
        float alpha = __expf(mrun - mnew);
        lrun *= alpha;
#pragma unroll
        for (int c = 0; c < 4; ++c) {
            ov[c].x *= alpha; ov[c].y *= alpha; ov[c].z *= alpha; ov[c].w *= alpha;
        }
        mrun = mnew;
#pragma unroll
        for (int c = 0; c < 16; ++c) {
            float4 s4 = *(const float4*)&Ss[qi][c * 4];
            float pj[4];
            pj[0] = __expf(s4.x - mnew);
            pj[1] = __expf(s4.y - mnew);
            pj[2] = __expf(s4.z - mnew);
            pj[3] = __expf(s4.w - mnew);
            lrun += pj[0] + pj[1] + pj[2] + pj[3];
#pragma unroll
            for (int kk = 0; kk < 4; ++kk) {
                int j = c * 4 + kk;
                float pv = pj[kk];
#pragma unroll
                for (int d4 = 0; d4 < 4; ++d4) {
                    float4 vv = *(const float4*)&Vs[j][p * 16 + d4 * 4];
                    ov[d4].x += pv * vv.x; ov[d4].y += pv * vv.y;
                    ov[d4].z += pv * vv.z; ov[d4].w += pv * vv.w;
                }
            }
        }
    }
    float inv = 1.f / lrun;
    float4* orow = (float4*)(o + (size_t)qg * 2048 + h * 64 + p * 16);
#pragma unroll
    for (int c = 0; c < 4; ++c) {
        float4 t = ov[c];
        t.x *= inv; t.y *= inv; t.z *= inv; t.w *= inv;
        orow[c] = t;
    }
}

// ---------------- launcher ----------------
extern "C" void kernel_launch(void* const* d_in, const int* in_sizes, int n_in,
                              void* d_out, int out_size, void* d_ws, size_t ws_size,
                              hipStream_t stream) {
    const float* x        = (const float*)d_in[0];
    const float* wq       = (const float*)d_in[1];
    const float* sq       = (const float*)d_in[2];
    const float* Aq       = (const float*)d_in[3];
    const float* Bq       = (const float*)d_in[4];
    const float* wk       = (const float*)d_in[5];
    const float* sk       = (const float*)d_in[6];
    const float* Ak       = (const float*)d_in[7];
    const float* Bk       = (const float*)d_in[8];
    const float* wv       = (const float*)d_in[9];
    const float* sv       = (const float*)d_in[10];
    const float* masks    = (const float*)d_in[11];
    const float* router_w = (const float*)d_in[12];
    const float* wo       = (const float*)d_in[13];
    const float* so       = (const float*)d_in[14];
    const float* Ao       = (const float*)d_in[15];
    const float* Bo       = (const float*)d_in[16];
    const float* w1       = (const float*)d_in[17];
    const float* s1       = (const float*)d_in[18];
    const float* A1       = (const float*)d_in[19];
    const float* B1       = (const float*)d_in[20];
    const float* w2       = (const float*)d_in[21];
    const float* s2       = (const float*)d_in[22];
    const float* A2       = (const float*)d_in[23];
    const float* B2       = (const float*)d_in[24];

    float* ws   = (float*)d_ws;
    float* out  = (float*)d_out;
    float* xn   = ws + OFF_XN;
    float* qf   = ws + OFF_QF;
    float* kf   = ws + OFF_KF;
    float* qh   = ws + OFF_QH;
    float* kh   = ws + OFF_KH;
    float* vbuf = ws + OFF_V;
    float* obuf = ws + OFF_O;
    float* h1   = ws + OFF_H1;
    float* mbuf = ws + OFF_M;
    float* mu   = ws + OFF_MU;
    float* tvec = ws + OFF_T;
    float* gq   = ws + OFF_GQ;
    float* gk   = ws + OFF_GK;
    float* go   = ws + OFF_GO;
    float* g1   = ws + OFF_G1;
    float* g2   = ws + OFF_G2;
    float* wtop = ws + OFF_WTOP;
    int*   cnt  = (int*)(ws + OFF_CNT);
    int*   list = (int*)(ws + OFF_LIST);

    unsigned short* bb  = (unsigned short*)(ws + FP32_FLOATS);
    unsigned short* wqb = bb + BOFF_WQ;
    unsigned short* wkb = bb + BOFF_WK;
    unsigned short* wob = bb + BOFF_WO;
    unsigned short* w1b = bb + BOFF_W1;
    unsigned short* w2b = bb + BOFF_W2;
    unsigned short* xnb = bb + BOFF_XN;
    unsigned short* ob  = bb + BOFF_OB;
    unsigned short* mb  = bb + BOFF_MB;

    const bool fast = ws_size >= WS_NEED;

    hipMemsetAsync(cnt, 0, E_ * sizeof(int), stream);

    if (fast) {
        ternb_kernel<<<(D_ * D_ / 4) / 256, 256, 0, stream>>>(wq, (unsigned*)wqb, D_ * D_ / 4);
        ternb_kernel<<<(1024 * D_ / 4) / 256, 256, 0, stream>>>(wk, (unsigned*)wkb, 1024 * D_ / 4);
        ternb_kernel<<<(D_ * D_ / 4) / 256, 256, 0, stream>>>(wo, (unsigned*)wob, D_ * D_ / 4);
        ternb_kernel<<<(FF_ * D_ / 4) / 256, 256, 0, stream>>>(w1, (unsigned*)w1b, FF_ * D_ / 4);
        ternb_kernel<<<(D_ * FF_ / 4) / 256, 256, 0, stream>>>(w2, (unsigned*)w2b, D_ * FF_ / 4);
    }

    rms_kernel<<<S_, 256, 0, stream>>>(x, xn, D_);
    colmean_kernel<<<D_ / 256, 256, 0, stream>>>(xn, mu, S_, D_);

    // Q projection (split-bf16: score path needs fp32-grade accuracy)
    bmu_kernel<<<1, 256, 0, stream>>>(Bq, mu, tvec, D_);
    gate_kernel<<<D_ / 256, 256, 0, stream>>>(Aq, tvec, sq, gq, D_);
    if (fast) gemm_mfma_dbl<1><<<dim3(D_ / 128, S_ / 64), 256, 0, stream>>>(xn, wqb, gq, qf, S_, D_, D_);
    else      gemm_mfma_dbl<0><<<dim3(D_ / 128, S_ / 64), 256, 0, stream>>>(xn, wq, gq, qf, S_, D_, D_);

    // K projection (split-bf16)
    bmu_kernel<<<1, 256, 0, stream>>>(Bk, mu, tvec, D_);
    gate_kernel<<<1024 / 256, 256, 0, stream>>>(Ak, tvec, sk, gk, 1024);
    if (fast) gemm_mfma_dbl<1><<<dim3(1024 / 128, S_ / 64), 256, 0, stream>>>(xn, wkb, gk, kf, S_, 1024, D_);
    else      gemm_mfma_dbl<0><<<dim3(1024 / 128, S_ / 64), 256, 0, stream>>>(xn, wk, gk, kf, S_, 1024, D_);

    // V (MoE)
    router_kernel<<<S_, 256, 0, stream>>>(xn, router_w, wtop, cnt, list);
    moe_kernel<<<dim3(E_, 1024 / 16), 256, 0, stream>>>(xn, wv, sv, masks, wtop, cnt, list, vbuf);

    // RoPE + head transpose
    rope_kernel<<<(H_ * S_ * 32) / 256, 256, 0, stream>>>(qf, qh, H_);
    rope_kernel<<<(HKV_ * S_ * 32) / 256, 256, 0, stream>>>(kf, kh, HKV_);

    // attention
    attn2_kernel<<<dim3(H_, S_ / 64), 256, 0, stream>>>(qh, kh, vbuf, obuf);

    // output projection + residual (smooth path: single bf16)
    colmean_kernel<<<D_ / 256, 256, 0, stream>>>(obuf, mu, S_, D_);
    bmu_kernel<<<1, 256, 0, stream>>>(Bo, mu, tvec, D_);
    gate_kernel<<<D_ / 256, 256, 0, stream>>>(Ao, tvec, so, go, D_);
    if (fast) {
        cvtb_kernel<<<(S_ * D_ / 4) / 256, 256, 0, stream>>>(obuf, (unsigned*)ob, S_ * D_ / 4);
        gemm_mfma<1, 1><<<dim3(D_ / 128, S_ / 64), 256, 0, stream>>>(ob, wob, go, x, h1, S_, D_, D_);
    } else {
        gemm_mfma<1, 0><<<dim3(D_ / 128, S_ / 64), 256, 0, stream>>>(obuf, wo, go, x, h1, S_, D_, D_);
    }

    // MLP up (relu^2)
    rms_kernel<<<S_, 256, 0, stream>>>(h1, xn, D_);
    colmean_kernel<<<D_ / 256, 256, 0, stream>>>(xn, mu, S_, D_);
    bmu_kernel<<<1, 256, 0, stream>>>(B1, mu, tvec, D_);
    gate_kernel<<<FF_ / 256, 256, 0, stream>>>(A1, tvec, s1, g1, FF_);
    if (fast) {
        cvtb_kernel<<<(S_ * D_ / 4) / 256, 256, 0, stream>>>(xn, (unsigned*)xnb, S_ * D_ / 4);
        gemm_mfma<2, 1><<<dim3(FF_ / 128, S_ / 64), 256, 0, stream>>>(xnb, w1b, g1, nullptr, mbuf, S_, FF_, D_);
    } else {
        gemm_mfma<2, 0><<<dim3(FF_ / 128, S_ / 64), 256, 0, stream>>>(xn, w1, g1, nullptr, mbuf, S_, FF_, D_);
    }

    // MLP down + residual -> out
    colmean_kernel<<<FF_ / 256, 256, 0, stream>>>(mbuf, mu, S_, FF_);
    bmu_kernel<<<1, 256, 0, stream>>>(B2, mu, tvec, FF_);
    gate_kernel<<<D_ / 256, 256, 0, stream>>>(A2, tvec, s2, g2, D_);
    if (fast) {
        cvtb_kernel<<<(S_ * FF_ / 4) / 256, 256, 0, stream>>>(mbuf, (unsigned*)mb, S_ * FF_ / 4);
        gemm_mfma<1, 1><<<dim3(D_ / 128, S_ / 64), 256, 0, stream>>>(mb, w2b, g2, h1, out, S_, D_, FF_);
    } else {
        gemm_mfma<1, 0><<<dim3(D_ / 128, S_ / 64), 256, 0, stream>>>(mbuf, w2, g2, h1, out, S_, D_, FF_);
    }
}

// Round 4
// 3261.517 us; speedup vs baseline: 1.7824x; 1.2490x over previous
//
#include <hip/hip_runtime.h>

// ---------------- problem constants ----------------
#define D_    2048
#define S_    1024
#define H_    32
#define HKV_  16
#define HD_   64
#define E_    32
#define R_    32
#define FF_   8192

// ---------------- workspace layout ----------------
constexpr size_t MEG = 1u << 20;
// fp32 region (float offsets)
constexpr size_t OFF_XN = 0;          // 2M
constexpr size_t OFF_QF = 2 * MEG;    // 2M
constexpr size_t OFF_KF = 4 * MEG;    // 1M
constexpr size_t OFF_QH = 5 * MEG;    // 2M
constexpr size_t OFF_KH = 7 * MEG;    // 1M
constexpr size_t OFF_V  = 8 * MEG;    // 1M
constexpr size_t OFF_O  = 9 * MEG;    // 2M
constexpr size_t OFF_H1 = 11 * MEG;   // 2M
constexpr size_t OFF_M  = 2 * MEG;    // 8M MLP mid — overlays QF..O (dead by then)
constexpr size_t OFF_SM = 13 * MEG;
constexpr size_t OFF_MU   = OFF_SM;
constexpr size_t OFF_T    = OFF_SM + 8192;
constexpr size_t OFF_GQ   = OFF_SM + 8224;
constexpr size_t OFF_GK   = OFF_SM + 10272;
constexpr size_t OFF_GO   = OFF_SM + 11296;
constexpr size_t OFF_G1   = OFF_SM + 13344;
constexpr size_t OFF_G2   = OFF_SM + 21536;
constexpr size_t OFF_WTOP = OFF_SM + 23584;
constexpr size_t OFF_CNT  = OFF_SM + 24608;
constexpr size_t OFF_LIST = OFF_SM + 24640;
// bf16 region begins at float offset 14M (ushort offsets from bb)
constexpr size_t FP32_FLOATS = 14 * MEG;
constexpr size_t BOFF_WQ = 0;                    // 4M
constexpr size_t BOFF_WK = 4 * MEG;              // 2M
constexpr size_t BOFF_WO = 6 * MEG;              // 4M
constexpr size_t BOFF_W1 = 10 * MEG;             // 16M
constexpr size_t BOFF_W2 = 26 * MEG;             // 16M
constexpr size_t BOFF_XN = 42 * MEG;             // 2M
constexpr size_t BOFF_OB = 44 * MEG;             // 2M
constexpr size_t BOFF_MB = 46 * MEG;             // 8M
constexpr size_t BF16_USHORTS = 54 * MEG;
constexpr size_t WS_NEED = FP32_FLOATS * 4 + BF16_USHORTS * 2;

typedef __attribute__((ext_vector_type(8))) short bf16x8;
typedef __attribute__((ext_vector_type(4))) float f32x4;

__device__ __forceinline__ float ternf(float w) {
    // clip(round(w/0.5), -1, 1); round half-to-even == rintf
    return __builtin_amdgcn_fmed3f(rintf(w + w), -1.f, 1.f);
}
__device__ __forceinline__ unsigned bfpk2(float a, float b) {
    unsigned ua = __float_as_uint(a), ub = __float_as_uint(b);
    ua = (ua + 0x7fffu + ((ua >> 16) & 1u)) >> 16;
    ub = (ub + 0x7fffu + ((ub >> 16) & 1u)) & 0xffff0000u;
    return ua | ub;
}
__device__ __forceinline__ unsigned short bf1(float a) {
    unsigned ua = __float_as_uint(a);
    return (unsigned short)((ua + 0x7fffu + ((ua >> 16) & 1u)) >> 16);
}
// split fp32 pair into (hi, lo) bf16 pairs: a ~= hi + lo to ~2^-17 rel
__device__ __forceinline__ void split_pack(float a, float b, unsigned& hi, unsigned& lo) {
    unsigned ua = __float_as_uint(a), ub = __float_as_uint(b);
    unsigned ha = (ua + 0x7fffu + ((ua >> 16) & 1u)) & 0xffff0000u;
    unsigned hb = (ub + 0x7fffu + ((ub >> 16) & 1u)) & 0xffff0000u;
    hi = (ha >> 16) | hb;
    lo = bfpk2(a - __uint_as_float(ha), b - __uint_as_float(hb));
}
__device__ __forceinline__ void split4(float4 v, uint2& hi, uint2& lo) {
    unsigned h0, l0, h1, l1;
    split_pack(v.x, v.y, h0, l0);
    split_pack(v.z, v.w, h1, l1);
    hi = make_uint2(h0, h1); lo = make_uint2(l0, l1);
}

// ---------------- RMSNorm ----------------
__global__ void rms_kernel(const float* __restrict__ x, float* __restrict__ y, int ncols) {
    int row = blockIdx.x;
    const float* xr = x + (size_t)row * ncols;
    float ss = 0.f;
    for (int i = threadIdx.x; i < ncols; i += 256) { float v = xr[i]; ss += v * v; }
    __shared__ float red[256];
    red[threadIdx.x] = ss; __syncthreads();
    for (int s = 128; s > 0; s >>= 1) {
        if (threadIdx.x < s) red[threadIdx.x] += red[threadIdx.x + s];
        __syncthreads();
    }
    float scale = rsqrtf(red[0] / (float)ncols + 1e-6f);
    float* yr = y + (size_t)row * ncols;
    for (int i = threadIdx.x; i < ncols; i += 256) yr[i] = xr[i] * scale;
}

// ---------------- column mean ----------------
__global__ void colmean_kernel(const float* __restrict__ X, float* __restrict__ mu, int M, int N) {
    int c = blockIdx.x * 256 + threadIdx.x;
    if (c >= N) return;
    float s = 0.f;
    for (int r = 0; r < M; ++r) s += X[(size_t)r * N + c];
    mu[c] = s / (float)M;
}

// ---------------- t = B(RxK) @ mu ----------------
__global__ void bmu_kernel(const float* __restrict__ Bm, const float* __restrict__ mu,
                           float* __restrict__ t, int K) {
    int lane = threadIdx.x & 63, wave = threadIdx.x >> 6;
    for (int r = wave; r < R_; r += 4) {
        float s = 0.f;
        const float* br = Bm + (size_t)r * K;
        for (int k = lane; k < K; k += 64) s += br[k] * mu[k];
        for (int off = 32; off > 0; off >>= 1) s += __shfl_down(s, off);
        if (lane == 0) t[r] = s;
    }
}

// ---------------- g[o] = scale[o] + A[o,:] . t ----------------
__global__ void gate_kernel(const float* __restrict__ A, const float* __restrict__ t,
                            const float* __restrict__ scale, float* __restrict__ g, int N) {
    int o = blockIdx.x * 256 + threadIdx.x;
    if (o >= N) return;
    float s = 0.f;
#pragma unroll
    for (int r = 0; r < R_; ++r) s += A[(size_t)o * R_ + r] * t[r];
    g[o] = scale[o] + s;
}

// ---------------- converts ----------------
__global__ void cvtb_kernel(const float* __restrict__ x, unsigned* __restrict__ y, int n4) {
    int i = blockIdx.x * 256 + threadIdx.x;
    if (i >= n4) return;
    float4 v = ((const float4*)x)[i];
    ((uint2*)y)[i] = make_uint2(bfpk2(v.x, v.y), bfpk2(v.z, v.w));
}
__global__ void ternb_kernel(const float* __restrict__ w, unsigned* __restrict__ y, int n4) {
    int i = blockIdx.x * 256 + threadIdx.x;
    if (i >= n4) return;
    float4 v = ((const float4*)w)[i];
    ((uint2*)y)[i] = make_uint2(bfpk2(ternf(v.x), ternf(v.y)),
                                bfpk2(ternf(v.z), ternf(v.w)));
}

// ---------------- single-bf16 MFMA GEMM: C = g[n]*(X . tern(W)^T) ----------------
template<int MODE, int PRE>
__global__ __launch_bounds__(256) void gemm_mfma(
        const void* __restrict__ Xv, const void* __restrict__ Wv,
        const float* __restrict__ g, const float* __restrict__ resid,
        float* __restrict__ C, int M, int N, int K) {
    __shared__ unsigned short As[64 * 32];
    __shared__ unsigned short Bs[128 * 32];
    int tid = threadIdx.x;
    int lane = tid & 63, wave = tid >> 6;
    int wm = wave & 1, wn = wave >> 1;
    int m0 = blockIdx.y * 64, n0 = blockIdx.x * 128;
    f32x4 acc[2][4];
#pragma unroll
    for (int i = 0; i < 2; ++i)
#pragma unroll
        for (int j = 0; j < 4; ++j) { f32x4 z = {0.f, 0.f, 0.f, 0.f}; acc[i][j] = z; }

    for (int k0 = 0; k0 < K; k0 += 32) {
        if (PRE) {
            const unsigned short* X = (const unsigned short*)Xv;
            const unsigned short* W = (const unsigned short*)Wv;
            {
                int row = tid >> 2, cg = tid & 3;
                *(uint4*)&As[row * 32 + cg * 8] =
                    *(const uint4*)&X[(size_t)(m0 + row) * K + k0 + cg * 8];
            }
#pragma unroll
            for (int it = 0; it < 2; ++it) {
                int idx = tid + it * 256;
                int row = idx >> 2, cg = idx & 3;
                *(uint4*)&Bs[row * 32 + cg * 8] =
                    *(const uint4*)&W[(size_t)(n0 + row) * K + k0 + cg * 8];
            }
        } else {
            const float* X = (const float*)Xv;
            const float* W = (const float*)Wv;
#pragma unroll
            for (int it = 0; it < 2; ++it) {
                int idx = tid + it * 256;
                int row = idx >> 3, cg = idx & 7;
                float4 v = *(const float4*)&X[(size_t)(m0 + row) * K + k0 + cg * 4];
                *(uint2*)&As[row * 32 + cg * 4] =
                    make_uint2(bfpk2(v.x, v.y), bfpk2(v.z, v.w));
            }
#pragma unroll
            for (int it = 0; it < 4; ++it) {
                int idx = tid + it * 256;
                int row = idx >> 3, cg = idx & 7;
                float4 v = *(const float4*)&W[(size_t)(n0 + row) * K + k0 + cg * 4];
                *(uint2*)&Bs[row * 32 + cg * 4] =
                    make_uint2(bfpk2(ternf(v.x), ternf(v.y)),
                               bfpk2(ternf(v.z), ternf(v.w)));
            }
        }
        __syncthreads();
        bf16x8 a[2], b[4];
#pragma unroll
        for (int mi = 0; mi < 2; ++mi)
            a[mi] = *(const bf16x8*)&As[(wm * 32 + mi * 16 + (lane & 15)) * 32 + (lane >> 4) * 8];
#pragma unroll
        for (int ni = 0; ni < 4; ++ni)
            b[ni] = *(const bf16x8*)&Bs[(wn * 64 + ni * 16 + (lane & 15)) * 32 + (lane >> 4) * 8];
#pragma unroll
        for (int mi = 0; mi < 2; ++mi)
#pragma unroll
            for (int ni = 0; ni < 4; ++ni)
                acc[mi][ni] = __builtin_amdgcn_mfma_f32_16x16x32_bf16(
                    a[mi], b[ni], acc[mi][ni], 0, 0, 0);
        __syncthreads();
    }
#pragma unroll
    for (int mi = 0; mi < 2; ++mi) {
        int rowb = m0 + wm * 32 + mi * 16 + (lane >> 4) * 4;
#pragma unroll
        for (int ni = 0; ni < 4; ++ni) {
            int col = n0 + wn * 64 + ni * 16 + (lane & 15);
            float gg = g[col];
#pragma unroll
            for (int rr = 0; rr < 4; ++rr) {
                int row = rowb + rr;
                float y = acc[mi][ni][rr] * gg;
                if (MODE == 1) y += resid[(size_t)row * N + col];
                if (MODE == 2) { float r = fmaxf(y, 0.f); y = r * r; }
                C[(size_t)row * N + col] = y;
            }
        }
    }
}

// ---------------- split-bf16 (double) MFMA GEMM — fp32-grade accuracy ----------------
template<int PREW>
__global__ __launch_bounds__(256) void gemm_mfma_dbl(
        const float* __restrict__ X, const void* __restrict__ Wv,
        const float* __restrict__ g, float* __restrict__ C, int M, int N, int K) {
    __shared__ unsigned short Ah[64 * 32];
    __shared__ unsigned short Al[64 * 32];
    __shared__ unsigned short Bs[128 * 32];
    int tid = threadIdx.x;
    int lane = tid & 63, wave = tid >> 6;
    int wm = wave & 1, wn = wave >> 1;
    int m0 = blockIdx.y * 64, n0 = blockIdx.x * 128;
    f32x4 acc[2][4];
#pragma unroll
    for (int i = 0; i < 2; ++i)
#pragma unroll
        for (int j = 0; j < 4; ++j) { f32x4 z = {0.f, 0.f, 0.f, 0.f}; acc[i][j] = z; }

    for (int k0 = 0; k0 < K; k0 += 32) {
#pragma unroll
        for (int it = 0; it < 2; ++it) {
            int idx = tid + it * 256;
            int row = idx >> 3, cg = idx & 7;
            float4 v = *(const float4*)&X[(size_t)(m0 + row) * K + k0 + cg * 4];
            uint2 hi, lo;
            split4(v, hi, lo);
            *(uint2*)&Ah[row * 32 + cg * 4] = hi;
            *(uint2*)&Al[row * 32 + cg * 4] = lo;
        }
        if (PREW) {
            const unsigned short* W = (const unsigned short*)Wv;
#pragma unroll
            for (int it = 0; it < 2; ++it) {
                int idx = tid + it * 256;
                int row = idx >> 2, cg = idx & 3;
                *(uint4*)&Bs[row * 32 + cg * 8] =
                    *(const uint4*)&W[(size_t)(n0 + row) * K + k0 + cg * 8];
            }
        } else {
            const float* W = (const float*)Wv;
#pragma unroll
            for (int it = 0; it < 4; ++it) {
                int idx = tid + it * 256;
                int row = idx >> 3, cg = idx & 7;
                float4 v = *(const float4*)&W[(size_t)(n0 + row) * K + k0 + cg * 4];
                *(uint2*)&Bs[row * 32 + cg * 4] =
                    make_uint2(bfpk2(ternf(v.x), ternf(v.y)),
                               bfpk2(ternf(v.z), ternf(v.w)));
            }
        }
        __syncthreads();
        bf16x8 ah[2], al[2], b[4];
#pragma unroll
        for (int mi = 0; mi < 2; ++mi) {
            int off = (wm * 32 + mi * 16 + (lane & 15)) * 32 + (lane >> 4) * 8;
            ah[mi] = *(const bf16x8*)&Ah[off];
            al[mi] = *(const bf16x8*)&Al[off];
        }
#pragma unroll
        for (int ni = 0; ni < 4; ++ni)
            b[ni] = *(const bf16x8*)&Bs[(wn * 64 + ni * 16 + (lane & 15)) * 32 + (lane >> 4) * 8];
#pragma unroll
        for (int mi = 0; mi < 2; ++mi)
#pragma unroll
            for (int ni = 0; ni < 4; ++ni) {
                acc[mi][ni] = __builtin_amdgcn_mfma_f32_16x16x32_bf16(
                    al[mi], b[ni], acc[mi][ni], 0, 0, 0);
                acc[mi][ni] = __builtin_amdgcn_mfma_f32_16x16x32_bf16(
                    ah[mi], b[ni], acc[mi][ni], 0, 0, 0);
            }
        __syncthreads();
    }
#pragma unroll
    for (int mi = 0; mi < 2; ++mi) {
        int rowb = m0 + wm * 32 + mi * 16 + (lane >> 4) * 4;
#pragma unroll
        for (int ni = 0; ni < 4; ++ni) {
            int col = n0 + wn * 64 + ni * 16 + (lane & 15);
            float gg = g[col];
#pragma unroll
            for (int rr = 0; rr < 4; ++rr)
                C[(size_t)(rowb + rr) * N + col] = acc[mi][ni][rr] * gg;
        }
    }
}

// ---------------- router ----------------
__global__ void router_kernel(const float* __restrict__ xn, const float* __restrict__ rw,
                              float* __restrict__ wtop, int* __restrict__ cnt,
                              int* __restrict__ list) {
    int t = blockIdx.x;
    const float* xr = xn + (size_t)t * D_;
    __shared__ float logits[E_];
    int lane = threadIdx.x & 63, wave = threadIdx.x >> 6;
    for (int e = wave; e < E_; e += 4) {
        float s = 0.f;
        const float* wr = rw + (size_t)e * D_;
        for (int k = lane; k < D_; k += 64) s += xr[k] * wr[k];
        for (int off = 32; off > 0; off >>= 1) s += __shfl_down(s, off);
        if (lane == 0) logits[e] = s;
    }
    __syncthreads();
    if (threadIdx.x == 0) {
        float mx = logits[0]; int mi = 0;
        for (int e = 1; e < E_; ++e) if (logits[e] > mx) { mx = logits[e]; mi = e; }
        float sum = 0.f;
        for (int e = 0; e < E_; ++e) sum += expf(logits[e] - mx);
        wtop[t] = 1.f / sum;
        int pos = atomicAdd(&cnt[mi], 1);
        list[mi * S_ + pos] = t;
    }
}

// ---------------- value MoE ----------------
__global__ __launch_bounds__(256) void moe_kernel(
        const float* __restrict__ xn, const float* __restrict__ wv,
        const float* __restrict__ sv, const float* __restrict__ masks,
        const float* __restrict__ wtop, const int* __restrict__ cnt,
        const int* __restrict__ list, float* __restrict__ vout) {
    int e = blockIdx.x;
    int o0 = blockIdx.y * 16;
    __shared__ char wqs[16 * 2048];
    __shared__ float xs[2048];
    int tid = threadIdx.x;
    const float* mbase = masks + (size_t)e * 1024 * 2048;
#pragma unroll
    for (int p = 0; p < 32; ++p) {
        int i = tid + p * 256;
        int o = i >> 9;
        int d = (i & 511) << 2;
        const float4 w4 = *(const float4*)(wv + (size_t)(o0 + o) * 2048 + d);
        const float4 m4 = *(const float4*)(mbase + (size_t)(o0 + o) * 2048 + d);
        char4 pk;
        pk.x = (char)(ternf(w4.x) * m4.x);
        pk.y = (char)(ternf(w4.y) * m4.y);
        pk.z = (char)(ternf(w4.z) * m4.z);
        pk.w = (char)(ternf(w4.w) * m4.w);
        *(char4*)&wqs[(size_t)o * 2048 + d] = pk;
    }
    int n = cnt[e];
    int lane = tid & 63, wave = tid >> 6;
    for (int j = 0; j < n; ++j) {
        int t = list[e * S_ + j];
        __syncthreads();
        for (int p = tid; p < 512; p += 256)
            *(float4*)&xs[p * 4] = *(const float4*)(xn + (size_t)t * 2048 + p * 4);
        __syncthreads();
        float gate = wtop[t];
#pragma unroll
        for (int i = 0; i < 4; ++i) {
            int o = wave * 4 + i;
            float s = 0.f;
#pragma unroll
            for (int it = 0; it < 8; ++it) {
                int d = it * 256 + lane * 4;
                char4 pk = *(const char4*)&wqs[o * 2048 + d];
                float4 xv = *(const float4*)&xs[d];
                s += xv.x * (float)pk.x + xv.y * (float)pk.y +
                     xv.z * (float)pk.z + xv.w * (float)pk.w;
            }
            for (int off = 32; off > 0; off >>= 1) s += __shfl_down(s, off);
            if (lane == 0) {
                int oo = o0 + o;
                int kvh = oo >> 6, dd = oo & 63;
                vout[((size_t)kvh * S_ + t) * 64 + dd] = gate * sv[oo] * s;
            }
        }
    }
}

// ---------------- RoPE + transpose ----------------
__global__ void rope_kernel(const float* __restrict__ inp, float* __restrict__ outp, int nheads) {
    int i = blockIdx.x * 256 + threadIdx.x;
    int p = i & 31;
    int s = (i >> 5) & 1023;
    int h = i >> 15;
    if (h >= nheads) return;
    int stride = nheads * 64;
    const float* irow = inp + (size_t)s * stride + h * 64;
    float x1 = irow[p], x2 = irow[32 + p];
    float fr = expf(-(float)p * 0.28782313662425575f);
    float ang = (float)s * fr;
    float sn, cs;
    sincosf(ang, &sn, &cs);
    float* orow = outp + ((size_t)h * S_ + s) * 64;
    orow[p]      = x1 * cs + x2 * sn;
    orow[32 + p] = -x1 * sn + x2 * cs;
}

// ---------------- MFMA flash attention ----------------
// Block = (head, 64-query tile), 4 waves x 16 queries. QK^T in split-bf16
// (3 MFMAs/chunk, fp32-grade scores — argmax-critical), online softmax in
// C-layout regs, PV in single bf16 against V^T in LDS.
__global__ __launch_bounds__(256) void attn3_kernel(
        const float* __restrict__ q, const float* __restrict__ k,
        const float* __restrict__ v, float* __restrict__ o) {
    int h = blockIdx.x;
    int qt = gridDim.y - 1 - blockIdx.y;   // heavy blocks first
    int kvh = h >> 1;
    const float* kb = k + (size_t)kvh * S_ * 64;
    const float* vb = v + (size_t)kvh * S_ * 64;
    __shared__ unsigned short Khi[64 * 72];
    __shared__ unsigned short Klo[64 * 72];
    __shared__ unsigned short Vt[64 * 72];     // Vt[dim][key]
    __shared__ unsigned short Ps[4][16 * 72];  // per-wave P tile
    int tid = threadIdx.x;
    int lane = tid & 63, wave = tid >> 6;
    int lm = lane & 15, lg = lane >> 4;

    // Q fragments (hi+lo split), rows = wave's 16 queries
    bf16x8 qhi[2], qlo[2];
    {
        int qrow = qt * 64 + wave * 16 + lm;
        const float* qp = q + ((size_t)h * S_ + qrow) * 64;
#pragma unroll
        for (int c = 0; c < 2; ++c) {
            float4 v0 = *(const float4*)&qp[c * 32 + lg * 8];
            float4 v1 = *(const float4*)&qp[c * 32 + lg * 8 + 4];
            union { bf16x8 b; uint2 u[2]; } uh, ul;
            split4(v0, uh.u[0], ul.u[0]);
            split4(v1, uh.u[1], ul.u[1]);
            qhi[c] = uh.b; qlo[c] = ul.b;
        }
    }
    f32x4 oacc[4];
#pragma unroll
    for (int n = 0; n < 4; ++n) { f32x4 z = {0.f, 0.f, 0.f, 0.f}; oacc[n] = z; }
    float mrun[4], lrun[4];
#pragma unroll
    for (int r = 0; r < 4; ++r) { mrun[r] = -1e30f; lrun[r] = 0.f; }

    int ntile = qt + 1;
    for (int kt = 0; kt < ntile; ++kt) {
        int j0 = kt * 64;
        __syncthreads();
        {   // stage K (split hi/lo) and V^T; thread: key=lane, dims wave*16..+15
            int key = lane, dg = wave;
            const float* kr = kb + (size_t)(j0 + key) * 64 + dg * 16;
            const float* vr = vb + (size_t)(j0 + key) * 64 + dg * 16;
            float4 k0 = ((const float4*)kr)[0], k1 = ((const float4*)kr)[1];
            float4 k2 = ((const float4*)kr)[2], k3 = ((const float4*)kr)[3];
            union { uint4 u; uint2 d[2]; } H0, H1, L0, L1;
            split4(k0, H0.d[0], L0.d[0]); split4(k1, H0.d[1], L0.d[1]);
            split4(k2, H1.d[0], L1.d[0]); split4(k3, H1.d[1], L1.d[1]);
            *(uint4*)&Khi[key * 72 + dg * 16]     = H0.u;
            *(uint4*)&Khi[key * 72 + dg * 16 + 8] = H1.u;
            *(uint4*)&Klo[key * 72 + dg * 16]     = L0.u;
            *(uint4*)&Klo[key * 72 + dg * 16 + 8] = L1.u;
            float vl[16];
            *(float4*)&vl[0]  = ((const float4*)vr)[0];
            *(float4*)&vl[4]  = ((const float4*)vr)[1];
            *(float4*)&vl[8]  = ((const float4*)vr)[2];
            *(float4*)&vl[12] = ((const float4*)vr)[3];
#pragma unroll
            for (int i = 0; i < 16; ++i)
                Vt[(dg * 16 + i) * 72 + key] = bf1(vl[i]);
        }
        __syncthreads();

        // ---- QK^T (split-bf16, 3 MFMAs per chunk) ----
        f32x4 sv[4];
#pragma unroll
        for (int n = 0; n < 4; ++n) {
            f32x4 s = {0.f, 0.f, 0.f, 0.f};
#pragma unroll
            for (int c = 0; c < 2; ++c) {
                int off = (n * 16 + lm) * 72 + c * 32 + lg * 8;
                bf16x8 bkh = *(const bf16x8*)&Khi[off];
                bf16x8 bkl = *(const bf16x8*)&Klo[off];
                s = __builtin_amdgcn_mfma_f32_16x16x32_bf16(qlo[c], bkh, s, 0, 0, 0);
                s = __builtin_amdgcn_mfma_f32_16x16x32_bf16(qhi[c], bkl, s, 0, 0, 0);
                s = __builtin_amdgcn_mfma_f32_16x16x32_bf16(qhi[c], bkh, s, 0, 0, 0);
            }
            sv[n] = s;
        }
        // scale + causal mask (diagonal tile only)
#pragma unroll
        for (int n = 0; n < 4; ++n) {
            int kglob = j0 + n * 16 + lm;
#pragma unroll
            for (int r = 0; r < 4; ++r) {
                float s = sv[n][r] * 0.125f;
                if (kt == qt) {
                    int qrow_r = qt * 64 + wave * 16 + lg * 4 + r;
                    if (kglob > qrow_r) s = -1e30f;
                }
                sv[n][r] = s;
            }
        }
        // ---- online softmax (rows = lg*4+r, cols across 16 lanes x 4 n) ----
        float rmax[4];
#pragma unroll
        for (int r = 0; r < 4; ++r) {
            float m = fmaxf(fmaxf(sv[0][r], sv[1][r]), fmaxf(sv[2][r], sv[3][r]));
#pragma unroll
            for (int off = 1; off < 16; off <<= 1)
                m = fmaxf(m, __shfl_xor(m, off));
            rmax[r] = m;
        }
        float alpha[4], rsum[4];
#pragma unroll
        for (int r = 0; r < 4; ++r) {
            float mnew = fmaxf(mrun[r], rmax[r]);
            alpha[r] = __expf(mrun[r] - mnew);
            mrun[r] = mnew;
            rsum[r] = 0.f;
        }
#pragma unroll
        for (int n = 0; n < 4; ++n)
#pragma unroll
            for (int r = 0; r < 4; ++r) {
                float p = __expf(sv[n][r] - mrun[r]);
                sv[n][r] = p;
                rsum[r] += p;
            }
#pragma unroll
        for (int r = 0; r < 4; ++r) {
#pragma unroll
            for (int off = 1; off < 16; off <<= 1)
                rsum[r] += __shfl_xor(rsum[r], off);
            lrun[r] = lrun[r] * alpha[r] + rsum[r];
        }
#pragma unroll
        for (int n = 0; n < 4; ++n)
#pragma unroll
            for (int r = 0; r < 4; ++r)
                oacc[n][r] *= alpha[r];
        // ---- P -> LDS (C-layout rows -> A-layout) ----
#pragma unroll
        for (int n = 0; n < 4; ++n)
#pragma unroll
            for (int r = 0; r < 4; ++r)
                Ps[wave][(lg * 4 + r) * 72 + n * 16 + lm] = bf1(sv[n][r]);
        bf16x8 ap[2];
#pragma unroll
        for (int c = 0; c < 2; ++c)
            ap[c] = *(const bf16x8*)&Ps[wave][lm * 72 + c * 32 + lg * 8];
        // ---- PV ----
#pragma unroll
        for (int n = 0; n < 4; ++n) {
#pragma unroll
            for (int c = 0; c < 2; ++c) {
                bf16x8 bv = *(const bf16x8*)&Vt[(n * 16 + lm) * 72 + c * 32 + lg * 8];
                oacc[n] = __builtin_amdgcn_mfma_f32_16x16x32_bf16(ap[c], bv, oacc[n], 0, 0, 0);
            }
        }
    }
    // ---- epilogue ----
    float inv[4];
#pragma unroll
    for (int r = 0; r < 4; ++r) inv[r] = 1.f / lrun[r];
#pragma unroll
    for (int n = 0; n < 4; ++n)
#pragma unroll
        for (int r = 0; r < 4; ++r) {
            int row = qt * 64 + wave * 16 + lg * 4 + r;
            o[(size_t)row * 2048 + h * 64 + n * 16 + lm] = oacc[n][r] * inv[r];
        }
}

// ---------------- launcher ----------------
extern "C" void kernel_launch(void* const* d_in, const int* in_sizes, int n_in,
                              void* d_out, int out_size, void* d_ws, size_t ws_size,
                              hipStream_t stream) {
    const float* x        = (const float*)d_in[0];
    const float* wq       = (const float*)d_in[1];
    const float* sq       = (const float*)d_in[2];
    const float* Aq       = (const float*)d_in[3];
    const float* Bq       = (const float*)d_in[4];
    const float* wk       = (const float*)d_in[5];
    const float* sk       = (const float*)d_in[6];
    const float* Ak       = (const float*)d_in[7];
    const float* Bk       = (const float*)d_in[8];
    const float* wv       = (const float*)d_in[9];
    const float* sv       = (const float*)d_in[10];
    const float* masks    = (const float*)d_in[11];
    const float* router_w = (const float*)d_in[12];
    const float* wo       = (const float*)d_in[13];
    const float* so       = (const float*)d_in[14];
    const float* Ao       = (const float*)d_in[15];
    const float* Bo       = (const float*)d_in[16];
    const float* w1       = (const float*)d_in[17];
    const float* s1       = (const float*)d_in[18];
    const float* A1       = (const float*)d_in[19];
    const float* B1       = (const float*)d_in[20];
    const float* w2       = (const float*)d_in[21];
    const float* s2       = (const float*)d_in[22];
    const float* A2       = (const float*)d_in[23];
    const float* B2       = (const float*)d_in[24];

    float* ws   = (float*)d_ws;
    float* out  = (float*)d_out;
    float* xn   = ws + OFF_XN;
    float* qf   = ws + OFF_QF;
    float* kf   = ws + OFF_KF;
    float* qh   = ws + OFF_QH;
    float* kh   = ws + OFF_KH;
    float* vbuf = ws + OFF_V;
    float* obuf = ws + OFF_O;
    float* h1   = ws + OFF_H1;
    float* mbuf = ws + OFF_M;
    float* mu   = ws + OFF_MU;
    float* tvec = ws + OFF_T;
    float* gq   = ws + OFF_GQ;
    float* gk   = ws + OFF_GK;
    float* go   = ws + OFF_GO;
    float* g1   = ws + OFF_G1;
    float* g2   = ws + OFF_G2;
    float* wtop = ws + OFF_WTOP;
    int*   cnt  = (int*)(ws + OFF_CNT);
    int*   list = (int*)(ws + OFF_LIST);

    unsigned short* bb  = (unsigned short*)(ws + FP32_FLOATS);
    unsigned short* wqb = bb + BOFF_WQ;
    unsigned short* wkb = bb + BOFF_WK;
    unsigned short* wob = bb + BOFF_WO;
    unsigned short* w1b = bb + BOFF_W1;
    unsigned short* w2b = bb + BOFF_W2;
    unsigned short* xnb = bb + BOFF_XN;
    unsigned short* ob  = bb + BOFF_OB;
    unsigned short* mb  = bb + BOFF_MB;

    const bool fast = ws_size >= WS_NEED;

    hipMemsetAsync(cnt, 0, E_ * sizeof(int), stream);

    if (fast) {
        ternb_kernel<<<(D_ * D_ / 4) / 256, 256, 0, stream>>>(wq, (unsigned*)wqb, D_ * D_ / 4);
        ternb_kernel<<<(1024 * D_ / 4) / 256, 256, 0, stream>>>(wk, (unsigned*)wkb, 1024 * D_ / 4);
        ternb_kernel<<<(D_ * D_ / 4) / 256, 256, 0, stream>>>(wo, (unsigned*)wob, D_ * D_ / 4);
        ternb_kernel<<<(FF_ * D_ / 4) / 256, 256, 0, stream>>>(w1, (unsigned*)w1b, FF_ * D_ / 4);
        ternb_kernel<<<(D_ * FF_ / 4) / 256, 256, 0, stream>>>(w2, (unsigned*)w2b, D_ * FF_ / 4);
    }

    rms_kernel<<<S_, 256, 0, stream>>>(x, xn, D_);
    colmean_kernel<<<D_ / 256, 256, 0, stream>>>(xn, mu, S_, D_);

    // Q projection (split-bf16: score path needs fp32-grade accuracy)
    bmu_kernel<<<1, 256, 0, stream>>>(Bq, mu, tvec, D_);
    gate_kernel<<<D_ / 256, 256, 0, stream>>>(Aq, tvec, sq, gq, D_);
    if (fast) gemm_mfma_dbl<1><<<dim3(D_ / 128, S_ / 64), 256, 0, stream>>>(xn, wqb, gq, qf, S_, D_, D_);
    else      gemm_mfma_dbl<0><<<dim3(D_ / 128, S_ / 64), 256, 0, stream>>>(xn, wq, gq, qf, S_, D_, D_);

    // K projection (split-bf16)
    bmu_kernel<<<1, 256, 0, stream>>>(Bk, mu, tvec, D_);
    gate_kernel<<<1024 / 256, 256, 0, stream>>>(Ak, tvec, sk, gk, 1024);
    if (fast) gemm_mfma_dbl<1><<<dim3(1024 / 128, S_ / 64), 256, 0, stream>>>(xn, wkb, gk, kf, S_, 1024, D_);
    else      gemm_mfma_dbl<0><<<dim3(1024 / 128, S_ / 64), 256, 0, stream>>>(xn, wk, gk, kf, S_, 1024, D_);

    // V (MoE)
    router_kernel<<<S_, 256, 0, stream>>>(xn, router_w, wtop, cnt, list);
    moe_kernel<<<dim3(E_, 1024 / 16), 256, 0, stream>>>(xn, wv, sv, masks, wtop, cnt, list, vbuf);

    // RoPE + head transpose
    rope_kernel<<<(H_ * S_ * 32) / 256, 256, 0, stream>>>(qf, qh, H_);
    rope_kernel<<<(HKV_ * S_ * 32) / 256, 256, 0, stream>>>(kf, kh, HKV_);

    // attention (MFMA flash)
    attn3_kernel<<<dim3(H_, S_ / 64), 256, 0, stream>>>(qh, kh, vbuf, obuf);

    // output projection + residual (smooth path: single bf16)
    colmean_kernel<<<D_ / 256, 256, 0, stream>>>(obuf, mu, S_, D_);
    bmu_kernel<<<1, 256, 0, stream>>>(Bo, mu, tvec, D_);
    gate_kernel<<<D_ / 256, 256, 0, stream>>>(Ao, tvec, so, go, D_);
    if (fast) {
        cvtb_kernel<<<(S_ * D_ / 4) / 256, 256, 0, stream>>>(obuf, (unsigned*)ob, S_ * D_ / 4);
        gemm_mfma<1, 1><<<dim3(D_ / 128, S_ / 64), 256, 0, stream>>>(ob, wob, go, x, h1, S_, D_, D_);
    } else {
        gemm_mfma<1, 0><<<dim3(D_ / 128, S_ / 64), 256, 0, stream>>>(obuf, wo, go, x, h1, S_, D_, D_);
    }

    // MLP up (relu^2)
    rms_kernel<<<S_, 256, 0, stream>>>(h1, xn, D_);
    colmean_kernel<<<D_ / 256, 256, 0, stream>>>(xn, mu, S_, D_);
    bmu_kernel<<<1, 256, 0, stream>>>(B1, mu, tvec, D_);
    gate_kernel<<<FF_ / 256, 256, 0, stream>>>(A1, tvec, s1, g1, FF_);
    if (fast) {
        cvtb_kernel<<<(S_ * D_ / 4) / 256, 256, 0, stream>>>(xn, (unsigned*)xnb, S_ * D_ / 4);
        gemm_mfma<2, 1><<<dim3(FF_ / 128, S_ / 64), 256, 0, stream>>>(xnb, w1b, g1, nullptr, mbuf, S_, FF_, D_);
    } else {
        gemm_mfma<2, 0><<<dim3(FF_ / 128, S_ / 64), 256, 0, stream>>>(xn, w1, g1, nullptr, mbuf, S_, FF_, D_);
    }

    // MLP down + residual -> out
    colmean_kernel<<<FF_ / 256, 256, 0, stream>>>(mbuf, mu, S_, FF_);
    bmu_kernel<<<1, 256, 0, stream>>>(B2, mu, tvec, FF_);
    gate_kernel<<<D_ / 256, 256, 0, stream>>>(A2, tvec, s2, g2, D_);
    if (fast) {
        cvtb_kernel<<<(S_ * FF_ / 4) / 256, 256, 0, stream>>>(mbuf, (unsigned*)mb, S_ * FF_ / 4);
        gemm_mfma<1, 1><<<dim3(D_ / 128, S_ / 64), 256, 0, stream>>>(mb, w2b, g2, h1, out, S_, D_, FF_);
    } else {
        gemm_mfma<1, 0><<<dim3(D_ / 128, S_ / 64), 256, 0, stream>>>(mbuf, w2, g2, h1, out, S_, D_, FF_);
    }
}

// Round 5
// 1757.927 us; speedup vs baseline: 3.3070x; 1.8553x over previous
//
#include <hip/hip_runtime.h>

// ---------------- problem constants ----------------
#define D_    2048
#define S_    1024
#define H_    32
#define HKV_  16
#define HD_   64
#define E_    32
#define R_    32
#define FF_   8192

// ---------------- workspace layout ----------------
constexpr size_t MEG = 1u << 20;
// fp32 region (float offsets)
constexpr size_t OFF_XN = 0;          // 2M
constexpr size_t OFF_QF = 2 * MEG;    // 2M
constexpr size_t OFF_KF = 4 * MEG;    // 1M
constexpr size_t OFF_QH = 5 * MEG;    // 2M
constexpr size_t OFF_KH = 7 * MEG;    // 1M
constexpr size_t OFF_V  = 8 * MEG;    // 1M
constexpr size_t OFF_O  = 9 * MEG;    // 2M
constexpr size_t OFF_H1 = 11 * MEG;   // 2M
constexpr size_t OFF_M  = 2 * MEG;    // 8M MLP mid — overlays QF..O (dead by then)
constexpr size_t OFF_SM = 13 * MEG;
constexpr size_t OFF_MU   = OFF_SM;
constexpr size_t OFF_T    = OFF_SM + 8192;
constexpr size_t OFF_GQ   = OFF_SM + 8224;
constexpr size_t OFF_GK   = OFF_SM + 10272;
constexpr size_t OFF_GO   = OFF_SM + 11296;
constexpr size_t OFF_G1   = OFF_SM + 13344;
constexpr size_t OFF_G2   = OFF_SM + 21536;
constexpr size_t OFF_WTOP = OFF_SM + 23584;
constexpr size_t OFF_CNT  = OFF_SM + 24608;
constexpr size_t OFF_LIST = OFF_SM + 24640;
// bf16 region begins at float offset 14M (ushort offsets from bb)
constexpr size_t FP32_FLOATS = 14 * MEG;
constexpr size_t BOFF_WQ = 0;                    // 4M
constexpr size_t BOFF_WK = 4 * MEG;              // 2M
constexpr size_t BOFF_WO = 6 * MEG;              // 4M
constexpr size_t BOFF_W1 = 10 * MEG;             // 16M
constexpr size_t BOFF_W2 = 26 * MEG;             // 16M
constexpr size_t BOFF_XN = 42 * MEG;             // 2M
constexpr size_t BOFF_OB = 44 * MEG;             // 2M
constexpr size_t BOFF_MB = 46 * MEG;             // 8M
constexpr size_t BF16_USHORTS = 54 * MEG;
constexpr size_t WS_NEED = FP32_FLOATS * 4 + BF16_USHORTS * 2;

typedef __attribute__((ext_vector_type(8))) short bf16x8;
typedef __attribute__((ext_vector_type(4))) float f32x4;

__device__ __forceinline__ float ternf(float w) {
    // clip(round(w/0.5), -1, 1); round half-to-even == rintf
    return __builtin_amdgcn_fmed3f(rintf(w + w), -1.f, 1.f);
}
__device__ __forceinline__ unsigned bfpk2(float a, float b) {
    unsigned ua = __float_as_uint(a), ub = __float_as_uint(b);
    ua = (ua + 0x7fffu + ((ua >> 16) & 1u)) >> 16;
    ub = (ub + 0x7fffu + ((ub >> 16) & 1u)) & 0xffff0000u;
    return ua | ub;
}
__device__ __forceinline__ unsigned short bf1(float a) {
    unsigned ua = __float_as_uint(a);
    return (unsigned short)((ua + 0x7fffu + ((ua >> 16) & 1u)) >> 16);
}
// split fp32 pair into (hi, lo) bf16 pairs: a ~= hi + lo to ~2^-17 rel
__device__ __forceinline__ void split_pack(float a, float b, unsigned& hi, unsigned& lo) {
    unsigned ua = __float_as_uint(a), ub = __float_as_uint(b);
    unsigned ha = (ua + 0x7fffu + ((ua >> 16) & 1u)) & 0xffff0000u;
    unsigned hb = (ub + 0x7fffu + ((ub >> 16) & 1u)) & 0xffff0000u;
    hi = (ha >> 16) | hb;
    lo = bfpk2(a - __uint_as_float(ha), b - __uint_as_float(hb));
}
__device__ __forceinline__ void split4(float4 v, uint2& hi, uint2& lo) {
    unsigned h0, l0, h1, l1;
    split_pack(v.x, v.y, h0, l0);
    split_pack(v.z, v.w, h1, l1);
    hi = make_uint2(h0, h1); lo = make_uint2(l0, l1);
}

// ---------------- RMSNorm ----------------
__global__ void rms_kernel(const float* __restrict__ x, float* __restrict__ y, int ncols) {
    int row = blockIdx.x;
    const float* xr = x + (size_t)row * ncols;
    float ss = 0.f;
    for (int i = threadIdx.x; i < ncols; i += 256) { float v = xr[i]; ss += v * v; }
    __shared__ float red[256];
    red[threadIdx.x] = ss; __syncthreads();
    for (int s = 128; s > 0; s >>= 1) {
        if (threadIdx.x < s) red[threadIdx.x] += red[threadIdx.x + s];
        __syncthreads();
    }
    float scale = rsqrtf(red[0] / (float)ncols + 1e-6f);
    float* yr = y + (size_t)row * ncols;
    for (int i = threadIdx.x; i < ncols; i += 256) yr[i] = xr[i] * scale;
}

// ---------------- column mean: grid N/64, block = 64 cols x 4 rowgroups ----------------
__global__ void colmean_kernel(const float* __restrict__ X, float* __restrict__ mu, int M, int N) {
    int c = blockIdx.x * 64 + (threadIdx.x & 63);
    int rg = threadIdx.x >> 6;
    float s = 0.f;
    for (int r = rg; r < M; r += 4) s += X[(size_t)r * N + c];
    __shared__ float red[4][64];
    red[rg][threadIdx.x & 63] = s;
    __syncthreads();
    if (threadIdx.x < 64) {
        float v = red[0][threadIdx.x] + red[1][threadIdx.x] +
                  red[2][threadIdx.x] + red[3][threadIdx.x];
        mu[blockIdx.x * 64 + threadIdx.x] = v / (float)M;
    }
}

// ---------------- t[r] = B[r,:] . mu  (grid = R_ blocks) ----------------
__global__ void bmu_kernel(const float* __restrict__ Bm, const float* __restrict__ mu,
                           float* __restrict__ t, int K) {
    int r = blockIdx.x;
    const float* br = Bm + (size_t)r * K;
    float s = 0.f;
    for (int k = threadIdx.x; k < K; k += 256) s += br[k] * mu[k];
    __shared__ float red[256];
    red[threadIdx.x] = s; __syncthreads();
    for (int st = 128; st > 0; st >>= 1) {
        if (threadIdx.x < st) red[threadIdx.x] += red[threadIdx.x + st];
        __syncthreads();
    }
    if (threadIdx.x == 0) t[r] = red[0];
}

// ---------------- g[o] = scale[o] + A[o,:] . t ----------------
__global__ void gate_kernel(const float* __restrict__ A, const float* __restrict__ t,
                            const float* __restrict__ scale, float* __restrict__ g, int N) {
    int o = blockIdx.x * 256 + threadIdx.x;
    if (o >= N) return;
    float s = 0.f;
#pragma unroll
    for (int r = 0; r < R_; ++r) s += A[(size_t)o * R_ + r] * t[r];
    g[o] = scale[o] + s;
}

// ---------------- converts ----------------
__global__ void cvtb_kernel(const float* __restrict__ x, unsigned* __restrict__ y, int n4) {
    int i = blockIdx.x * 256 + threadIdx.x;
    if (i >= n4) return;
    float4 v = ((const float4*)x)[i];
    ((uint2*)y)[i] = make_uint2(bfpk2(v.x, v.y), bfpk2(v.z, v.w));
}
__global__ void ternb_kernel(const float* __restrict__ w, unsigned* __restrict__ y, int n4) {
    int i = blockIdx.x * 256 + threadIdx.x;
    if (i >= n4) return;
    float4 v = ((const float4*)w)[i];
    ((uint2*)y)[i] = make_uint2(bfpk2(ternf(v.x), ternf(v.y)),
                                bfpk2(ternf(v.z), ternf(v.w)));
}

// ---------------- single-bf16 MFMA GEMM: C = g[n]*(X . tern(W)^T) ----------------
template<int MODE, int PRE>
__global__ __launch_bounds__(256) void gemm_mfma(
        const void* __restrict__ Xv, const void* __restrict__ Wv,
        const float* __restrict__ g, const float* __restrict__ resid,
        float* __restrict__ C, int M, int N, int K) {
    __shared__ unsigned short As[64 * 32];
    __shared__ unsigned short Bs[128 * 32];
    int tid = threadIdx.x;
    int lane = tid & 63, wave = tid >> 6;
    int wm = wave & 1, wn = wave >> 1;
    int m0 = blockIdx.y * 64, n0 = blockIdx.x * 128;
    f32x4 acc[2][4];
#pragma unroll
    for (int i = 0; i < 2; ++i)
#pragma unroll
        for (int j = 0; j < 4; ++j) { f32x4 z = {0.f, 0.f, 0.f, 0.f}; acc[i][j] = z; }

    for (int k0 = 0; k0 < K; k0 += 32) {
        if (PRE) {
            const unsigned short* X = (const unsigned short*)Xv;
            const unsigned short* W = (const unsigned short*)Wv;
            {
                int row = tid >> 2, cg = tid & 3;
                *(uint4*)&As[row * 32 + cg * 8] =
                    *(const uint4*)&X[(size_t)(m0 + row) * K + k0 + cg * 8];
            }
#pragma unroll
            for (int it = 0; it < 2; ++it) {
                int idx = tid + it * 256;
                int row = idx >> 2, cg = idx & 3;
                *(uint4*)&Bs[row * 32 + cg * 8] =
                    *(const uint4*)&W[(size_t)(n0 + row) * K + k0 + cg * 8];
            }
        } else {
            const float* X = (const float*)Xv;
            const float* W = (const float*)Wv;
#pragma unroll
            for (int it = 0; it < 2; ++it) {
                int idx = tid + it * 256;
                int row = idx >> 3, cg = idx & 7;
                float4 v = *(const float4*)&X[(size_t)(m0 + row) * K + k0 + cg * 4];
                *(uint2*)&As[row * 32 + cg * 4] =
                    make_uint2(bfpk2(v.x, v.y), bfpk2(v.z, v.w));
            }
#pragma unroll
            for (int it = 0; it < 4; ++it) {
                int idx = tid + it * 256;
                int row = idx >> 3, cg = idx & 7;
                float4 v = *(const float4*)&W[(size_t)(n0 + row) * K + k0 + cg * 4];
                *(uint2*)&Bs[row * 32 + cg * 4] =
                    make_uint2(bfpk2(ternf(v.x), ternf(v.y)),
                               bfpk2(ternf(v.z), ternf(v.w)));
            }
        }
        __syncthreads();
        bf16x8 a[2], b[4];
#pragma unroll
        for (int mi = 0; mi < 2; ++mi)
            a[mi] = *(const bf16x8*)&As[(wm * 32 + mi * 16 + (lane & 15)) * 32 + (lane >> 4) * 8];
#pragma unroll
        for (int ni = 0; ni < 4; ++ni)
            b[ni] = *(const bf16x8*)&Bs[(wn * 64 + ni * 16 + (lane & 15)) * 32 + (lane >> 4) * 8];
#pragma unroll
        for (int mi = 0; mi < 2; ++mi)
#pragma unroll
            for (int ni = 0; ni < 4; ++ni)
                acc[mi][ni] = __builtin_amdgcn_mfma_f32_16x16x32_bf16(
                    a[mi], b[ni], acc[mi][ni], 0, 0, 0);
        __syncthreads();
    }
#pragma unroll
    for (int mi = 0; mi < 2; ++mi) {
        int rowb = m0 + wm * 32 + mi * 16 + (lane >> 4) * 4;
#pragma unroll
        for (int ni = 0; ni < 4; ++ni) {
            int col = n0 + wn * 64 + ni * 16 + (lane & 15);
            float gg = g[col];
#pragma unroll
            for (int rr = 0; rr < 4; ++rr) {
                int row = rowb + rr;
                float y = acc[mi][ni][rr] * gg;
                if (MODE == 1) y += resid[(size_t)row * N + col];
                if (MODE == 2) { float r = fmaxf(y, 0.f); y = r * r; }
                C[(size_t)row * N + col] = y;
            }
        }
    }
}

// ---------------- split-bf16 (double) MFMA GEMM — fp32-grade accuracy ----------------
template<int PREW>
__global__ __launch_bounds__(256) void gemm_mfma_dbl(
        const float* __restrict__ X, const void* __restrict__ Wv,
        const float* __restrict__ g, float* __restrict__ C, int M, int N, int K) {
    __shared__ unsigned short Ah[64 * 32];
    __shared__ unsigned short Al[64 * 32];
    __shared__ unsigned short Bs[128 * 32];
    int tid = threadIdx.x;
    int lane = tid & 63, wave = tid >> 6;
    int wm = wave & 1, wn = wave >> 1;
    int m0 = blockIdx.y * 64, n0 = blockIdx.x * 128;
    f32x4 acc[2][4];
#pragma unroll
    for (int i = 0; i < 2; ++i)
#pragma unroll
        for (int j = 0; j < 4; ++j) { f32x4 z = {0.f, 0.f, 0.f, 0.f}; acc[i][j] = z; }

    for (int k0 = 0; k0 < K; k0 += 32) {
#pragma unroll
        for (int it = 0; it < 2; ++it) {
            int idx = tid + it * 256;
            int row = idx >> 3, cg = idx & 7;
            float4 v = *(const float4*)&X[(size_t)(m0 + row) * K + k0 + cg * 4];
            uint2 hi, lo;
            split4(v, hi, lo);
            *(uint2*)&Ah[row * 32 + cg * 4] = hi;
            *(uint2*)&Al[row * 32 + cg * 4] = lo;
        }
        if (PREW) {
            const unsigned short* W = (const unsigned short*)Wv;
#pragma unroll
            for (int it = 0; it < 2; ++it) {
                int idx = tid + it * 256;
                int row = idx >> 2, cg = idx & 3;
                *(uint4*)&Bs[row * 32 + cg * 8] =
                    *(const uint4*)&W[(size_t)(n0 + row) * K + k0 + cg * 8];
            }
        } else {
            const float* W = (const float*)Wv;
#pragma unroll
            for (int it = 0; it < 4; ++it) {
                int idx = tid + it * 256;
                int row = idx >> 3, cg = idx & 7;
                float4 v = *(const float4*)&W[(size_t)(n0 + row) * K + k0 + cg * 4];
                *(uint2*)&Bs[row * 32 + cg * 4] =
                    make_uint2(bfpk2(ternf(v.x), ternf(v.y)),
                               bfpk2(ternf(v.z), ternf(v.w)));
            }
        }
        __syncthreads();
        bf16x8 ah[2], al[2], b[4];
#pragma unroll
        for (int mi = 0; mi < 2; ++mi) {
            int off = (wm * 32 + mi * 16 + (lane & 15)) * 32 + (lane >> 4) * 8;
            ah[mi] = *(const bf16x8*)&Ah[off];
            al[mi] = *(const bf16x8*)&Al[off];
        }
#pragma unroll
        for (int ni = 0; ni < 4; ++ni)
            b[ni] = *(const bf16x8*)&Bs[(wn * 64 + ni * 16 + (lane & 15)) * 32 + (lane >> 4) * 8];
#pragma unroll
        for (int mi = 0; mi < 2; ++mi)
#pragma unroll
            for (int ni = 0; ni < 4; ++ni) {
                acc[mi][ni] = __builtin_amdgcn_mfma_f32_16x16x32_bf16(
                    al[mi], b[ni], acc[mi][ni], 0, 0, 0);
                acc[mi][ni] = __builtin_amdgcn_mfma_f32_16x16x32_bf16(
                    ah[mi], b[ni], acc[mi][ni], 0, 0, 0);
            }
        __syncthreads();
    }
#pragma unroll
    for (int mi = 0; mi < 2; ++mi) {
        int rowb = m0 + wm * 32 + mi * 16 + (lane >> 4) * 4;
#pragma unroll
        for (int ni = 0; ni < 4; ++ni) {
            int col = n0 + wn * 64 + ni * 16 + (lane & 15);
            float gg = g[col];
#pragma unroll
            for (int rr = 0; rr < 4; ++rr)
                C[(size_t)(rowb + rr) * N + col] = acc[mi][ni][rr] * gg;
        }
    }
}

// ---------------- router ----------------
__global__ void router_kernel(const float* __restrict__ xn, const float* __restrict__ rw,
                              float* __restrict__ wtop, int* __restrict__ cnt,
                              int* __restrict__ list) {
    int t = blockIdx.x;
    const float* xr = xn + (size_t)t * D_;
    __shared__ float logits[E_];
    int lane = threadIdx.x & 63, wave = threadIdx.x >> 6;
    for (int e = wave; e < E_; e += 4) {
        float s = 0.f;
        const float* wr = rw + (size_t)e * D_;
        for (int k = lane; k < D_; k += 64) s += xr[k] * wr[k];
        for (int off = 32; off > 0; off >>= 1) s += __shfl_down(s, off);
        if (lane == 0) logits[e] = s;
    }
    __syncthreads();
    if (threadIdx.x == 0) {
        float mx = logits[0]; int mi = 0;
        for (int e = 1; e < E_; ++e) if (logits[e] > mx) { mx = logits[e]; mi = e; }
        float sum = 0.f;
        for (int e = 0; e < E_; ++e) sum += expf(logits[e] - mx);
        wtop[t] = 1.f / sum;
        int pos = atomicAdd(&cnt[mi], 1);
        list[mi * S_ + pos] = t;
    }
}

// ---------------- value MoE ----------------
__global__ __launch_bounds__(256) void moe_kernel(
        const float* __restrict__ xn, const float* __restrict__ wv,
        const float* __restrict__ sv, const float* __restrict__ masks,
        const float* __restrict__ wtop, const int* __restrict__ cnt,
        const int* __restrict__ list, float* __restrict__ vout) {
    int e = blockIdx.x;
    int o0 = blockIdx.y * 16;
    __shared__ char wqs[16 * 2048];
    __shared__ float xs[2048];
    int tid = threadIdx.x;
    const float* mbase = masks + (size_t)e * 1024 * 2048;
#pragma unroll
    for (int p = 0; p < 32; ++p) {
        int i = tid + p * 256;
        int o = i >> 9;
        int d = (i & 511) << 2;
        const float4 w4 = *(const float4*)(wv + (size_t)(o0 + o) * 2048 + d);
        const float4 m4 = *(const float4*)(mbase + (size_t)(o0 + o) * 2048 + d);
        char4 pk;
        pk.x = (char)(ternf(w4.x) * m4.x);
        pk.y = (char)(ternf(w4.y) * m4.y);
        pk.z = (char)(ternf(w4.z) * m4.z);
        pk.w = (char)(ternf(w4.w) * m4.w);
        *(char4*)&wqs[(size_t)o * 2048 + d] = pk;
    }
    int n = cnt[e];
    int lane = tid & 63, wave = tid >> 6;
    for (int j = 0; j < n; ++j) {
        int t = list[e * S_ + j];
        __syncthreads();
        for (int p = tid; p < 512; p += 256)
            *(float4*)&xs[p * 4] = *(const float4*)(xn + (size_t)t * 2048 + p * 4);
        __syncthreads();
        float gate = wtop[t];
#pragma unroll
        for (int i = 0; i < 4; ++i) {
            int o = wave * 4 + i;
            float s = 0.f;
#pragma unroll
            for (int it = 0; it < 8; ++it) {
                int d = it * 256 + lane * 4;
                char4 pk = *(const char4*)&wqs[o * 2048 + d];
                float4 xv = *(const float4*)&xs[d];
                s += xv.x * (float)pk.x + xv.y * (float)pk.y +
                     xv.z * (float)pk.z + xv.w * (float)pk.w;
            }
            for (int off = 32; off > 0; off >>= 1) s += __shfl_down(s, off);
            if (lane == 0) {
                int oo = o0 + o;
                int kvh = oo >> 6, dd = oo & 63;
                vout[((size_t)kvh * S_ + t) * 64 + dd] = gate * sv[oo] * s;
            }
        }
    }
}

// ---------------- RoPE + transpose ----------------
__global__ void rope_kernel(const float* __restrict__ inp, float* __restrict__ outp, int nheads) {
    int i = blockIdx.x * 256 + threadIdx.x;
    int p = i & 31;
    int s = (i >> 5) & 1023;
    int h = i >> 15;
    if (h >= nheads) return;
    int stride = nheads * 64;
    const float* irow = inp + (size_t)s * stride + h * 64;
    float x1 = irow[p], x2 = irow[32 + p];
    float fr = expf(-(float)p * 0.28782313662425575f);
    float ang = (float)s * fr;
    float sn, cs;
    sincosf(ang, &sn, &cs);
    float* orow = outp + ((size_t)h * S_ + s) * 64;
    orow[p]      = x1 * cs + x2 * sn;
    orow[32 + p] = -x1 * sn + x2 * cs;
}

// ---------------- MFMA flash attention ----------------
__global__ __launch_bounds__(256) void attn3_kernel(
        const float* __restrict__ q, const float* __restrict__ k,
        const float* __restrict__ v, float* __restrict__ o) {
    int h = blockIdx.x;
    int qt = gridDim.y - 1 - blockIdx.y;   // heavy blocks first
    int kvh = h >> 1;
    const float* kb = k + (size_t)kvh * S_ * 64;
    const float* vb = v + (size_t)kvh * S_ * 64;
    __shared__ unsigned short Khi[64 * 72];
    __shared__ unsigned short Klo[64 * 72];
    __shared__ unsigned short Vt[64 * 72];     // Vt[dim][key]
    __shared__ unsigned short Ps[4][16 * 72];  // per-wave P tile
    int tid = threadIdx.x;
    int lane = tid & 63, wave = tid >> 6;
    int lm = lane & 15, lg = lane >> 4;

    bf16x8 qhi[2], qlo[2];
    {
        int qrow = qt * 64 + wave * 16 + lm;
        const float* qp = q + ((size_t)h * S_ + qrow) * 64;
#pragma unroll
        for (int c = 0; c < 2; ++c) {
            float4 v0 = *(const float4*)&qp[c * 32 + lg * 8];
            float4 v1 = *(const float4*)&qp[c * 32 + lg * 8 + 4];
            union { bf16x8 b; uint2 u[2]; } uh, ul;
            split4(v0, uh.u[0], ul.u[0]);
            split4(v1, uh.u[1], ul.u[1]);
            qhi[c] = uh.b; qlo[c] = ul.b;
        }
    }
    f32x4 oacc[4];
#pragma unroll
    for (int n = 0; n < 4; ++n) { f32x4 z = {0.f, 0.f, 0.f, 0.f}; oacc[n] = z; }
    float mrun[4], lrun[4];
#pragma unroll
    for (int r = 0; r < 4; ++r) { mrun[r] = -1e30f; lrun[r] = 0.f; }

    int ntile = qt + 1;
    for (int kt = 0; kt < ntile; ++kt) {
        int j0 = kt * 64;
        __syncthreads();
        {
            int key = lane, dg = wave;
            const float* kr = kb + (size_t)(j0 + key) * 64 + dg * 16;
            const float* vr = vb + (size_t)(j0 + key) * 64 + dg * 16;
            float4 k0 = ((const float4*)kr)[0], k1 = ((const float4*)kr)[1];
            float4 k2 = ((const float4*)kr)[2], k3 = ((const float4*)kr)[3];
            union { uint4 u; uint2 d[2]; } H0, H1, L0, L1;
            split4(k0, H0.d[0], L0.d[0]); split4(k1, H0.d[1], L0.d[1]);
            split4(k2, H1.d[0], L1.d[0]); split4(k3, H1.d[1], L1.d[1]);
            *(uint4*)&Khi[key * 72 + dg * 16]     = H0.u;
            *(uint4*)&Khi[key * 72 + dg * 16 + 8] = H1.u;
            *(uint4*)&Klo[key * 72 + dg * 16]     = L0.u;
            *(uint4*)&Klo[key * 72 + dg * 16 + 8] = L1.u;
            float vl[16];
            *(float4*)&vl[0]  = ((const float4*)vr)[0];
            *(float4*)&vl[4]  = ((const float4*)vr)[1];
            *(float4*)&vl[8]  = ((const float4*)vr)[2];
            *(float4*)&vl[12] = ((const float4*)vr)[3];
#pragma unroll
            for (int i = 0; i < 16; ++i)
                Vt[(dg * 16 + i) * 72 + key] = bf1(vl[i]);
        }
        __syncthreads();

        f32x4 sv[4];
#pragma unroll
        for (int n = 0; n < 4; ++n) {
            f32x4 s = {0.f, 0.f, 0.f, 0.f};
#pragma unroll
            for (int c = 0; c < 2; ++c) {
                int off = (n * 16 + lm) * 72 + c * 32 + lg * 8;
                bf16x8 bkh = *(const bf16x8*)&Khi[off];
                bf16x8 bkl = *(const bf16x8*)&Klo[off];
                s = __builtin_amdgcn_mfma_f32_16x16x32_bf16(qlo[c], bkh, s, 0, 0, 0);
                s = __builtin_amdgcn_mfma_f32_16x16x32_bf16(qhi[c], bkl, s, 0, 0, 0);
                s = __builtin_amdgcn_mfma_f32_16x16x32_bf16(qhi[c], bkh, s, 0, 0, 0);
            }
            sv[n] = s;
        }
#pragma unroll
        for (int n = 0; n < 4; ++n) {
            int kglob = j0 + n * 16 + lm;
#pragma unroll
            for (int r = 0; r < 4; ++r) {
                float s = sv[n][r] * 0.125f;
                if (kt == qt) {
                    int qrow_r = qt * 64 + wave * 16 + lg * 4 + r;
                    if (kglob > qrow_r) s = -1e30f;
                }
                sv[n][r] = s;
            }
        }
        float rmax[4];
#pragma unroll
        for (int r = 0; r < 4; ++r) {
            float m = fmaxf(fmaxf(sv[0][r], sv[1][r]), fmaxf(sv[2][r], sv[3][r]));
#pragma unroll
            for (int off = 1; off < 16; off <<= 1)
                m = fmaxf(m, __shfl_xor(m, off));
            rmax[r] = m;
        }
        float alpha[4], rsum[4];
#pragma unroll
        for (int r = 0; r < 4; ++r) {
            float mnew = fmaxf(mrun[r], rmax[r]);
            alpha[r] = __expf(mrun[r] - mnew);
            mrun[r] = mnew;
            rsum[r] = 0.f;
        }
#pragma unroll
        for (int n = 0; n < 4; ++n)
#pragma unroll
            for (int r = 0; r < 4; ++r) {
                float p = __expf(sv[n][r] - mrun[r]);
                sv[n][r] = p;
                rsum[r] += p;
            }
#pragma unroll
        for (int r = 0; r < 4; ++r) {
#pragma unroll
            for (int off = 1; off < 16; off <<= 1)
                rsum[r] += __shfl_xor(rsum[r], off);
            lrun[r] = lrun[r] * alpha[r] + rsum[r];
        }
#pragma unroll
        for (int n = 0; n < 4; ++n)
#pragma unroll
            for (int r = 0; r < 4; ++r)
                oacc[n][r] *= alpha[r];
#pragma unroll
        for (int n = 0; n < 4; ++n)
#pragma unroll
            for (int r = 0; r < 4; ++r)
                Ps[wave][(lg * 4 + r) * 72 + n * 16 + lm] = bf1(sv[n][r]);
        bf16x8 ap[2];
#pragma unroll
        for (int c = 0; c < 2; ++c)
            ap[c] = *(const bf16x8*)&Ps[wave][lm * 72 + c * 32 + lg * 8];
#pragma unroll
        for (int n = 0; n < 4; ++n) {
#pragma unroll
            for (int c = 0; c < 2; ++c) {
                bf16x8 bv = *(const bf16x8*)&Vt[(n * 16 + lm) * 72 + c * 32 + lg * 8];
                oacc[n] = __builtin_amdgcn_mfma_f32_16x16x32_bf16(ap[c], bv, oacc[n], 0, 0, 0);
            }
        }
    }
    float inv[4];
#pragma unroll
    for (int r = 0; r < 4; ++r) inv[r] = 1.f / lrun[r];
#pragma unroll
    for (int n = 0; n < 4; ++n)
#pragma unroll
        for (int r = 0; r < 4; ++r) {
            int row = qt * 64 + wave * 16 + lg * 4 + r;
            o[(size_t)row * 2048 + h * 64 + n * 16 + lm] = oacc[n][r] * inv[r];
        }
}

// ---------------- launcher ----------------
extern "C" void kernel_launch(void* const* d_in, const int* in_sizes, int n_in,
                              void* d_out, int out_size, void* d_ws, size_t ws_size,
                              hipStream_t stream) {
    const float* x        = (const float*)d_in[0];
    const float* wq       = (const float*)d_in[1];
    const float* sq       = (const float*)d_in[2];
    const float* Aq       = (const float*)d_in[3];
    const float* Bq       = (const float*)d_in[4];
    const float* wk       = (const float*)d_in[5];
    const float* sk       = (const float*)d_in[6];
    const float* Ak       = (const float*)d_in[7];
    const float* Bk       = (const float*)d_in[8];
    const float* wv       = (const float*)d_in[9];
    const float* sv       = (const float*)d_in[10];
    const float* masks    = (const float*)d_in[11];
    const float* router_w = (const float*)d_in[12];
    const float* wo       = (const float*)d_in[13];
    const float* so       = (const float*)d_in[14];
    const float* Ao       = (const float*)d_in[15];
    const float* Bo       = (const float*)d_in[16];
    const float* w1       = (const float*)d_in[17];
    const float* s1       = (const float*)d_in[18];
    const float* A1       = (const float*)d_in[19];
    const float* B1       = (const float*)d_in[20];
    const float* w2       = (const float*)d_in[21];
    const float* s2       = (const float*)d_in[22];
    const float* A2       = (const float*)d_in[23];
    const float* B2       = (const float*)d_in[24];

    float* ws   = (float*)d_ws;
    float* out  = (float*)d_out;
    float* xn   = ws + OFF_XN;
    float* qf   = ws + OFF_QF;
    float* kf   = ws + OFF_KF;
    float* qh   = ws + OFF_QH;
    float* kh   = ws + OFF_KH;
    float* vbuf = ws + OFF_V;
    float* obuf = ws + OFF_O;
    float* h1   = ws + OFF_H1;
    float* mbuf = ws + OFF_M;
    float* mu   = ws + OFF_MU;
    float* tvec = ws + OFF_T;
    float* gq   = ws + OFF_GQ;
    float* gk   = ws + OFF_GK;
    float* go   = ws + OFF_GO;
    float* g1   = ws + OFF_G1;
    float* g2   = ws + OFF_G2;
    float* wtop = ws + OFF_WTOP;
    int*   cnt  = (int*)(ws + OFF_CNT);
    int*   list = (int*)(ws + OFF_LIST);

    unsigned short* bb  = (unsigned short*)(ws + FP32_FLOATS);
    unsigned short* wqb = bb + BOFF_WQ;
    unsigned short* wkb = bb + BOFF_WK;
    unsigned short* wob = bb + BOFF_WO;
    unsigned short* w1b = bb + BOFF_W1;
    unsigned short* w2b = bb + BOFF_W2;
    unsigned short* xnb = bb + BOFF_XN;
    unsigned short* ob  = bb + BOFF_OB;
    unsigned short* mb  = bb + BOFF_MB;

    const bool fast = ws_size >= WS_NEED;

    hipMemsetAsync(cnt, 0, E_ * sizeof(int), stream);

    if (fast) {
        ternb_kernel<<<(D_ * D_ / 4) / 256, 256, 0, stream>>>(wq, (unsigned*)wqb, D_ * D_ / 4);
        ternb_kernel<<<(1024 * D_ / 4) / 256, 256, 0, stream>>>(wk, (unsigned*)wkb, 1024 * D_ / 4);
        ternb_kernel<<<(D_ * D_ / 4) / 256, 256, 0, stream>>>(wo, (unsigned*)wob, D_ * D_ / 4);
        ternb_kernel<<<(FF_ * D_ / 4) / 256, 256, 0, stream>>>(w1, (unsigned*)w1b, FF_ * D_ / 4);
        ternb_kernel<<<(D_ * FF_ / 4) / 256, 256, 0, stream>>>(w2, (unsigned*)w2b, D_ * FF_ / 4);
    }

    rms_kernel<<<S_, 256, 0, stream>>>(x, xn, D_);
    colmean_kernel<<<D_ / 64, 256, 0, stream>>>(xn, mu, S_, D_);

    // Q projection (split-bf16: score path needs fp32-grade accuracy)
    bmu_kernel<<<R_, 256, 0, stream>>>(Bq, mu, tvec, D_);
    gate_kernel<<<D_ / 256, 256, 0, stream>>>(Aq, tvec, sq, gq, D_);
    if (fast) gemm_mfma_dbl<1><<<dim3(D_ / 128, S_ / 64), 256, 0, stream>>>(xn, wqb, gq, qf, S_, D_, D_);
    else      gemm_mfma_dbl<0><<<dim3(D_ / 128, S_ / 64), 256, 0, stream>>>(xn, wq, gq, qf, S_, D_, D_);

    // K projection (split-bf16)
    bmu_kernel<<<R_, 256, 0, stream>>>(Bk, mu, tvec, D_);
    gate_kernel<<<1024 / 256, 256, 0, stream>>>(Ak, tvec, sk, gk, 1024);
    if (fast) gemm_mfma_dbl<1><<<dim3(1024 / 128, S_ / 64), 256, 0, stream>>>(xn, wkb, gk, kf, S_, 1024, D_);
    else      gemm_mfma_dbl<0><<<dim3(1024 / 128, S_ / 64), 256, 0, stream>>>(xn, wk, gk, kf, S_, 1024, D_);

    // V (MoE)
    router_kernel<<<S_, 256, 0, stream>>>(xn, router_w, wtop, cnt, list);
    moe_kernel<<<dim3(E_, 1024 / 16), 256, 0, stream>>>(xn, wv, sv, masks, wtop, cnt, list, vbuf);

    // RoPE + head transpose
    rope_kernel<<<(H_ * S_ * 32) / 256, 256, 0, stream>>>(qf, qh, H_);
    rope_kernel<<<(HKV_ * S_ * 32) / 256, 256, 0, stream>>>(kf, kh, HKV_);

    // attention (MFMA flash)
    attn3_kernel<<<dim3(H_, S_ / 64), 256, 0, stream>>>(qh, kh, vbuf, obuf);

    // output projection + residual (smooth path: single bf16)
    colmean_kernel<<<D_ / 64, 256, 0, stream>>>(obuf, mu, S_, D_);
    bmu_kernel<<<R_, 256, 0, stream>>>(Bo, mu, tvec, D_);
    gate_kernel<<<D_ / 256, 256, 0, stream>>>(Ao, tvec, so, go, D_);
    if (fast) {
        cvtb_kernel<<<(S_ * D_ / 4) / 256, 256, 0, stream>>>(obuf, (unsigned*)ob, S_ * D_ / 4);
        gemm_mfma<1, 1><<<dim3(D_ / 128, S_ / 64), 256, 0, stream>>>(ob, wob, go, x, h1, S_, D_, D_);
    } else {
        gemm_mfma<1, 0><<<dim3(D_ / 128, S_ / 64), 256, 0, stream>>>(obuf, wo, go, x, h1, S_, D_, D_);
    }

    // MLP up (relu^2)
    rms_kernel<<<S_, 256, 0, stream>>>(h1, xn, D_);
    colmean_kernel<<<D_ / 64, 256, 0, stream>>>(xn, mu, S_, D_);
    bmu_kernel<<<R_, 256, 0, stream>>>(B1, mu, tvec, D_);
    gate_kernel<<<FF_ / 256, 256, 0, stream>>>(A1, tvec, s1, g1, FF_);
    if (fast) {
        cvtb_kernel<<<(S_ * D_ / 4) / 256, 256, 0, stream>>>(xn, (unsigned*)xnb, S_ * D_ / 4);
        gemm_mfma<2, 1><<<dim3(FF_ / 128, S_ / 64), 256, 0, stream>>>(xnb, w1b, g1, nullptr, mbuf, S_, FF_, D_);
    } else {
        gemm_mfma<2, 0><<<dim3(FF_ / 128, S_ / 64), 256, 0, stream>>>(xn, w1, g1, nullptr, mbuf, S_, FF_, D_);
    }

    // MLP down + residual -> out
    colmean_kernel<<<FF_ / 64, 256, 0, stream>>>(mbuf, mu, S_, FF_);
    bmu_kernel<<<R_, 256, 0, stream>>>(B2, mu, tvec, FF_);
    gate_kernel<<<D_ / 256, 256, 0, stream>>>(A2, tvec, s2, g2, D_);
    if (fast) {
        cvtb_kernel<<<(S_ * FF_ / 4) / 256, 256, 0, stream>>>(mbuf, (unsigned*)mb, S_ * FF_ / 4);
        gemm_mfma<1, 1><<<dim3(D_ / 128, S_ / 64), 256, 0, stream>>>(mb, w2b, g2, h1, out, S_, D_, FF_);
    } else {
        gemm_mfma<1, 0><<<dim3(D_ / 128, S_ / 64), 256, 0, stream>>>(mbuf, w2, g2, h1, out, S_, D_, FF_);
    }
}

// Round 6
// 1477.110 us; speedup vs baseline: 3.9357x; 1.1901x over previous
//
#include <hip/hip_runtime.h>

// ---------------- problem constants ----------------
#define D_    2048
#define S_    1024
#define H_    32
#define HKV_  16
#define HD_   64
#define E_    32
#define R_    32
#define FF_   8192

// ---------------- workspace layout ----------------
constexpr size_t MEG = 1u << 20;
// fp32 region (float offsets)
constexpr size_t OFF_XN = 0;          // 2M
constexpr size_t OFF_QF = 2 * MEG;    // 2M
constexpr size_t OFF_KF = 4 * MEG;    // 1M
constexpr size_t OFF_QH = 5 * MEG;    // 2M
constexpr size_t OFF_KH = 7 * MEG;    // 1M
constexpr size_t OFF_V  = 8 * MEG;    // 1M
constexpr size_t OFF_O  = 9 * MEG;    // 2M
constexpr size_t OFF_H1 = 11 * MEG;   // 2M
constexpr size_t OFF_M  = 2 * MEG;    // 8M MLP mid — overlays QF..O (dead by then)
constexpr size_t OFF_SM = 13 * MEG;
constexpr size_t OFF_MU   = OFF_SM;
constexpr size_t OFF_T    = OFF_SM + 8192;
constexpr size_t OFF_GQ   = OFF_SM + 8224;
constexpr size_t OFF_GK   = OFF_SM + 10272;
constexpr size_t OFF_GO   = OFF_SM + 11296;
constexpr size_t OFF_G1   = OFF_SM + 13344;
constexpr size_t OFF_G2   = OFF_SM + 21536;
constexpr size_t OFF_WTOP = OFF_SM + 23584;
constexpr size_t OFF_CNT  = OFF_SM + 24608;
constexpr size_t OFF_LIST = OFF_SM + 24640;
// bf16 region begins at float offset 14M (ushort offsets from bb)
constexpr size_t FP32_FLOATS = 14 * MEG;
constexpr size_t BOFF_WQ = 0;                    // 4M
constexpr size_t BOFF_WK = 4 * MEG;              // 2M
constexpr size_t BOFF_WO = 6 * MEG;              // 4M
constexpr size_t BOFF_W1 = 10 * MEG;             // 16M
constexpr size_t BOFF_W2 = 26 * MEG;             // 16M
constexpr size_t BOFF_XN = 42 * MEG;             // 2M
constexpr size_t BOFF_OB = 44 * MEG;             // 2M
constexpr size_t BOFF_MB = 46 * MEG;             // 8M
constexpr size_t BF16_USHORTS = 54 * MEG;
constexpr size_t WS_NEED = FP32_FLOATS * 4 + BF16_USHORTS * 2;

typedef __attribute__((ext_vector_type(8))) short bf16x8;
typedef __attribute__((ext_vector_type(4))) float f32x4;

__device__ __forceinline__ float ternf(float w) {
    // clip(round(w/0.5), -1, 1); round half-to-even == rintf
    return __builtin_amdgcn_fmed3f(rintf(w + w), -1.f, 1.f);
}
__device__ __forceinline__ unsigned bfpk2(float a, float b) {
    unsigned ua = __float_as_uint(a), ub = __float_as_uint(b);
    ua = (ua + 0x7fffu + ((ua >> 16) & 1u)) >> 16;
    ub = (ub + 0x7fffu + ((ub >> 16) & 1u)) & 0xffff0000u;
    return ua | ub;
}
__device__ __forceinline__ unsigned short bf1(float a) {
    unsigned ua = __float_as_uint(a);
    return (unsigned short)((ua + 0x7fffu + ((ua >> 16) & 1u)) >> 16);
}
// split fp32 pair into (hi, lo) bf16 pairs: a ~= hi + lo to ~2^-17 rel
__device__ __forceinline__ void split_pack(float a, float b, unsigned& hi, unsigned& lo) {
    unsigned ua = __float_as_uint(a), ub = __float_as_uint(b);
    unsigned ha = (ua + 0x7fffu + ((ua >> 16) & 1u)) & 0xffff0000u;
    unsigned hb = (ub + 0x7fffu + ((ub >> 16) & 1u)) & 0xffff0000u;
    hi = (ha >> 16) | hb;
    lo = bfpk2(a - __uint_as_float(ha), b - __uint_as_float(hb));
}
__device__ __forceinline__ void split4(float4 v, uint2& hi, uint2& lo) {
    unsigned h0, l0, h1, l1;
    split_pack(v.x, v.y, h0, l0);
    split_pack(v.z, v.w, h1, l1);
    hi = make_uint2(h0, h1); lo = make_uint2(l0, l1);
}

// ---------------- RMSNorm ----------------
__global__ void rms_kernel(const float* __restrict__ x, float* __restrict__ y, int ncols) {
    int row = blockIdx.x;
    const float* xr = x + (size_t)row * ncols;
    float ss = 0.f;
    for (int i = threadIdx.x; i < ncols; i += 256) { float v = xr[i]; ss += v * v; }
    __shared__ float red[256];
    red[threadIdx.x] = ss; __syncthreads();
    for (int s = 128; s > 0; s >>= 1) {
        if (threadIdx.x < s) red[threadIdx.x] += red[threadIdx.x + s];
        __syncthreads();
    }
    float scale = rsqrtf(red[0] / (float)ncols + 1e-6f);
    float* yr = y + (size_t)row * ncols;
    for (int i = threadIdx.x; i < ncols; i += 256) yr[i] = xr[i] * scale;
}

// ---------------- column mean: grid N/64, block = 64 cols x 4 rowgroups ----------------
__global__ void colmean_kernel(const float* __restrict__ X, float* __restrict__ mu, int M, int N) {
    int c = blockIdx.x * 64 + (threadIdx.x & 63);
    int rg = threadIdx.x >> 6;
    float s = 0.f;
    for (int r = rg; r < M; r += 4) s += X[(size_t)r * N + c];
    __shared__ float red[4][64];
    red[rg][threadIdx.x & 63] = s;
    __syncthreads();
    if (threadIdx.x < 64) {
        float v = red[0][threadIdx.x] + red[1][threadIdx.x] +
                  red[2][threadIdx.x] + red[3][threadIdx.x];
        mu[blockIdx.x * 64 + threadIdx.x] = v / (float)M;
    }
}

// ---------------- t[r] = B[r,:] . mu  (grid = R_ blocks) ----------------
__global__ void bmu_kernel(const float* __restrict__ Bm, const float* __restrict__ mu,
                           float* __restrict__ t, int K) {
    int r = blockIdx.x;
    const float* br = Bm + (size_t)r * K;
    float s = 0.f;
    for (int k = threadIdx.x; k < K; k += 256) s += br[k] * mu[k];
    __shared__ float red[256];
    red[threadIdx.x] = s; __syncthreads();
    for (int st = 128; st > 0; st >>= 1) {
        if (threadIdx.x < st) red[threadIdx.x] += red[threadIdx.x + st];
        __syncthreads();
    }
    if (threadIdx.x == 0) t[r] = red[0];
}

// ---------------- g[o] = scale[o] + A[o,:] . t ----------------
__global__ void gate_kernel(const float* __restrict__ A, const float* __restrict__ t,
                            const float* __restrict__ scale, float* __restrict__ g, int N) {
    int o = blockIdx.x * 256 + threadIdx.x;
    if (o >= N) return;
    float s = 0.f;
#pragma unroll
    for (int r = 0; r < R_; ++r) s += A[(size_t)o * R_ + r] * t[r];
    g[o] = scale[o] + s;
}

// ---------------- converts ----------------
__global__ void cvtb_kernel(const float* __restrict__ x, unsigned* __restrict__ y, int n4) {
    int i = blockIdx.x * 256 + threadIdx.x;
    if (i >= n4) return;
    float4 v = ((const float4*)x)[i];
    ((uint2*)y)[i] = make_uint2(bfpk2(v.x, v.y), bfpk2(v.z, v.w));
}
__global__ void ternb_kernel(const float* __restrict__ w, unsigned* __restrict__ y, int n4) {
    int i = blockIdx.x * 256 + threadIdx.x;
    if (i >= n4) return;
    float4 v = ((const float4*)w)[i];
    ((uint2*)y)[i] = make_uint2(bfpk2(ternf(v.x), ternf(v.y)),
                                bfpk2(ternf(v.z), ternf(v.w)));
}

// ---------------- single-bf16 MFMA GEMM: C = g[n]*(X . tern(W)^T) ----------------
template<int MODE, int PRE>
__global__ __launch_bounds__(256) void gemm_mfma(
        const void* __restrict__ Xv, const void* __restrict__ Wv,
        const float* __restrict__ g, const float* __restrict__ resid,
        float* __restrict__ C, int M, int N, int K) {
    __shared__ unsigned short As[64 * 32];
    __shared__ unsigned short Bs[128 * 32];
    int tid = threadIdx.x;
    int lane = tid & 63, wave = tid >> 6;
    int wm = wave & 1, wn = wave >> 1;
    int m0 = blockIdx.y * 64, n0 = blockIdx.x * 128;
    f32x4 acc[2][4];
#pragma unroll
    for (int i = 0; i < 2; ++i)
#pragma unroll
        for (int j = 0; j < 4; ++j) { f32x4 z = {0.f, 0.f, 0.f, 0.f}; acc[i][j] = z; }

    for (int k0 = 0; k0 < K; k0 += 32) {
        if (PRE) {
            const unsigned short* X = (const unsigned short*)Xv;
            const unsigned short* W = (const unsigned short*)Wv;
            {
                int row = tid >> 2, cg = tid & 3;
                *(uint4*)&As[row * 32 + cg * 8] =
                    *(const uint4*)&X[(size_t)(m0 + row) * K + k0 + cg * 8];
            }
#pragma unroll
            for (int it = 0; it < 2; ++it) {
                int idx = tid + it * 256;
                int row = idx >> 2, cg = idx & 3;
                *(uint4*)&Bs[row * 32 + cg * 8] =
                    *(const uint4*)&W[(size_t)(n0 + row) * K + k0 + cg * 8];
            }
        } else {
            const float* X = (const float*)Xv;
            const float* W = (const float*)Wv;
#pragma unroll
            for (int it = 0; it < 2; ++it) {
                int idx = tid + it * 256;
                int row = idx >> 3, cg = idx & 7;
                float4 v = *(const float4*)&X[(size_t)(m0 + row) * K + k0 + cg * 4];
                *(uint2*)&As[row * 32 + cg * 4] =
                    make_uint2(bfpk2(v.x, v.y), bfpk2(v.z, v.w));
            }
#pragma unroll
            for (int it = 0; it < 4; ++it) {
                int idx = tid + it * 256;
                int row = idx >> 3, cg = idx & 7;
                float4 v = *(const float4*)&W[(size_t)(n0 + row) * K + k0 + cg * 4];
                *(uint2*)&Bs[row * 32 + cg * 4] =
                    make_uint2(bfpk2(ternf(v.x), ternf(v.y)),
                               bfpk2(ternf(v.z), ternf(v.w)));
            }
        }
        __syncthreads();
        bf16x8 a[2], b[4];
#pragma unroll
        for (int mi = 0; mi < 2; ++mi)
            a[mi] = *(const bf16x8*)&As[(wm * 32 + mi * 16 + (lane & 15)) * 32 + (lane >> 4) * 8];
#pragma unroll
        for (int ni = 0; ni < 4; ++ni)
            b[ni] = *(const bf16x8*)&Bs[(wn * 64 + ni * 16 + (lane & 15)) * 32 + (lane >> 4) * 8];
#pragma unroll
        for (int mi = 0; mi < 2; ++mi)
#pragma unroll
            for (int ni = 0; ni < 4; ++ni)
                acc[mi][ni] = __builtin_amdgcn_mfma_f32_16x16x32_bf16(
                    a[mi], b[ni], acc[mi][ni], 0, 0, 0);
        __syncthreads();
    }
#pragma unroll
    for (int mi = 0; mi < 2; ++mi) {
        int rowb = m0 + wm * 32 + mi * 16 + (lane >> 4) * 4;
#pragma unroll
        for (int ni = 0; ni < 4; ++ni) {
            int col = n0 + wn * 64 + ni * 16 + (lane & 15);
            float gg = g[col];
#pragma unroll
            for (int rr = 0; rr < 4; ++rr) {
                int row = rowb + rr;
                float y = acc[mi][ni][rr] * gg;
                if (MODE == 1) y += resid[(size_t)row * N + col];
                if (MODE == 2) { float r = fmaxf(y, 0.f); y = r * r; }
                C[(size_t)row * N + col] = y;
            }
        }
    }
}

// ---------------- split-bf16 (double) MFMA GEMM — fp32-grade accuracy ----------------
template<int PREW>
__global__ __launch_bounds__(256) void gemm_mfma_dbl(
        const float* __restrict__ X, const void* __restrict__ Wv,
        const float* __restrict__ g, float* __restrict__ C, int M, int N, int K) {
    __shared__ unsigned short Ah[64 * 32];
    __shared__ unsigned short Al[64 * 32];
    __shared__ unsigned short Bs[128 * 32];
    int tid = threadIdx.x;
    int lane = tid & 63, wave = tid >> 6;
    int wm = wave & 1, wn = wave >> 1;
    int m0 = blockIdx.y * 64, n0 = blockIdx.x * 128;
    f32x4 acc[2][4];
#pragma unroll
    for (int i = 0; i < 2; ++i)
#pragma unroll
        for (int j = 0; j < 4; ++j) { f32x4 z = {0.f, 0.f, 0.f, 0.f}; acc[i][j] = z; }

    for (int k0 = 0; k0 < K; k0 += 32) {
#pragma unroll
        for (int it = 0; it < 2; ++it) {
            int idx = tid + it * 256;
            int row = idx >> 3, cg = idx & 7;
            float4 v = *(const float4*)&X[(size_t)(m0 + row) * K + k0 + cg * 4];
            uint2 hi, lo;
            split4(v, hi, lo);
            *(uint2*)&Ah[row * 32 + cg * 4] = hi;
            *(uint2*)&Al[row * 32 + cg * 4] = lo;
        }
        if (PREW) {
            const unsigned short* W = (const unsigned short*)Wv;
#pragma unroll
            for (int it = 0; it < 2; ++it) {
                int idx = tid + it * 256;
                int row = idx >> 2, cg = idx & 3;
                *(uint4*)&Bs[row * 32 + cg * 8] =
                    *(const uint4*)&W[(size_t)(n0 + row) * K + k0 + cg * 8];
            }
        } else {
            const float* W = (const float*)Wv;
#pragma unroll
            for (int it = 0; it < 4; ++it) {
                int idx = tid + it * 256;
                int row = idx >> 3, cg = idx & 7;
                float4 v = *(const float4*)&W[(size_t)(n0 + row) * K + k0 + cg * 4];
                *(uint2*)&Bs[row * 32 + cg * 4] =
                    make_uint2(bfpk2(ternf(v.x), ternf(v.y)),
                               bfpk2(ternf(v.z), ternf(v.w)));
            }
        }
        __syncthreads();
        bf16x8 ah[2], al[2], b[4];
#pragma unroll
        for (int mi = 0; mi < 2; ++mi) {
            int off = (wm * 32 + mi * 16 + (lane & 15)) * 32 + (lane >> 4) * 8;
            ah[mi] = *(const bf16x8*)&Ah[off];
            al[mi] = *(const bf16x8*)&Al[off];
        }
#pragma unroll
        for (int ni = 0; ni < 4; ++ni)
            b[ni] = *(const bf16x8*)&Bs[(wn * 64 + ni * 16 + (lane & 15)) * 32 + (lane >> 4) * 8];
#pragma unroll
        for (int mi = 0; mi < 2; ++mi)
#pragma unroll
            for (int ni = 0; ni < 4; ++ni) {
                acc[mi][ni] = __builtin_amdgcn_mfma_f32_16x16x32_bf16(
                    al[mi], b[ni], acc[mi][ni], 0, 0, 0);
                acc[mi][ni] = __builtin_amdgcn_mfma_f32_16x16x32_bf16(
                    ah[mi], b[ni], acc[mi][ni], 0, 0, 0);
            }
        __syncthreads();
    }
#pragma unroll
    for (int mi = 0; mi < 2; ++mi) {
        int rowb = m0 + wm * 32 + mi * 16 + (lane >> 4) * 4;
#pragma unroll
        for (int ni = 0; ni < 4; ++ni) {
            int col = n0 + wn * 64 + ni * 16 + (lane & 15);
            float gg = g[col];
#pragma unroll
            for (int rr = 0; rr < 4; ++rr)
                C[(size_t)(rowb + rr) * N + col] = acc[mi][ni][rr] * gg;
        }
    }
}

// ---------------- router ----------------
__global__ void router_kernel(const float* __restrict__ xn, const float* __restrict__ rw,
                              float* __restrict__ wtop, int* __restrict__ cnt,
                              int* __restrict__ list) {
    int t = blockIdx.x;
    const float* xr = xn + (size_t)t * D_;
    __shared__ float logits[E_];
    int lane = threadIdx.x & 63, wave = threadIdx.x >> 6;
    for (int e = wave; e < E_; e += 4) {
        float s = 0.f;
        const float* wr = rw + (size_t)e * D_;
        for (int k = lane; k < D_; k += 64) s += xr[k] * wr[k];
        for (int off = 32; off > 0; off >>= 1) s += __shfl_down(s, off);
        if (lane == 0) logits[e] = s;
    }
    __syncthreads();
    if (threadIdx.x == 0) {
        float mx = logits[0]; int mi = 0;
        for (int e = 1; e < E_; ++e) if (logits[e] > mx) { mx = logits[e]; mi = e; }
        float sum = 0.f;
        for (int e = 0; e < E_; ++e) sum += expf(logits[e] - mx);
        wtop[t] = 1.f / sum;
        int pos = atomicAdd(&cnt[mi], 1);
        list[mi * S_ + pos] = t;
    }
}

// ---------------- value MoE (MFMA, bf16 x) ----------------
// Block = (expert, 16-output tile). Masked ternary weights staged ONCE in LDS
// as bf16 (exact). Tokens processed in 16-row MFMA tiles; K split across the
// 4 waves (512 each) with an LDS partial reduce.
__global__ __launch_bounds__(256) void moe_mfma_kernel(
        const unsigned short* __restrict__ xnb, const float* __restrict__ wv,
        const float* __restrict__ sv, const float* __restrict__ masks,
        const float* __restrict__ wtop, const int* __restrict__ cnt,
        const int* __restrict__ list, float* __restrict__ vout) {
    int e = blockIdx.x;
    int o0 = blockIdx.y * 16;
    constexpr int BSTR = 2056;                 // pad 8 ushorts: 2-way banks (free)
    __shared__ unsigned short Bs[16 * BSTR];   // 64.25 KB
    __shared__ float Cred[4][16][17];          // 4.25 KB
    int tid = threadIdx.x;
    int lane = tid & 63, wave = tid >> 6;
    int lm = lane & 15, lg = lane >> 4;
    const float* mbase = masks + (size_t)e * 1024 * 2048 + (size_t)o0 * 2048;
    const float* wbase = wv + (size_t)o0 * 2048;
#pragma unroll
    for (int p = 0; p < 32; ++p) {
        int i = tid + p * 256;     // float4-group over 16*512
        int o = i >> 9;
        int d = (i & 511) << 2;
        float4 w4 = *(const float4*)(wbase + (size_t)o * 2048 + d);
        float4 m4 = *(const float4*)(mbase + (size_t)o * 2048 + d);
        *(uint2*)&Bs[o * BSTR + d] = make_uint2(
            bfpk2(ternf(w4.x) * m4.x, ternf(w4.y) * m4.y),
            bfpk2(ternf(w4.z) * m4.z, ternf(w4.w) * m4.w));
    }
    int n = cnt[e];
    __syncthreads();
    int ntt = (n + 15) >> 4;
    for (int tt = 0; tt < ntt; ++tt) {
        int ti = tt * 16 + lm;
        int tok = list[e * S_ + min(ti, n - 1)];
        const unsigned short* xr = xnb + (size_t)tok * 2048;
        f32x4 acc = {0.f, 0.f, 0.f, 0.f};
        int kbase = wave * 512;
#pragma unroll
        for (int kc = 0; kc < 16; ++kc) {
            int k0 = kbase + kc * 32;
            bf16x8 a = *(const bf16x8*)&xr[k0 + lg * 8];
            bf16x8 b = *(const bf16x8*)&Bs[lm * BSTR + k0 + lg * 8];
            acc = __builtin_amdgcn_mfma_f32_16x16x32_bf16(a, b, acc, 0, 0, 0);
        }
#pragma unroll
        for (int r = 0; r < 4; ++r)
            Cred[wave][lg * 4 + r][lm] = acc[r];
        __syncthreads();
        {
            int row = tid >> 4, outn = tid & 15;
            int tidx = tt * 16 + row;
            if (tidx < n) {
                float vsum = Cred[0][row][outn] + Cred[1][row][outn]
                           + Cred[2][row][outn] + Cred[3][row][outn];
                int tk = list[e * S_ + tidx];
                int oo = o0 + outn;
                vout[((size_t)(oo >> 6) * S_ + tk) * 64 + (oo & 63)] =
                    wtop[tk] * sv[oo] * vsum;
            }
        }
        __syncthreads();
    }
}

// ---------------- value MoE (fallback, fp32 VALU) ----------------
__global__ __launch_bounds__(256) void moe_kernel(
        const float* __restrict__ xn, const float* __restrict__ wv,
        const float* __restrict__ sv, const float* __restrict__ masks,
        const float* __restrict__ wtop, const int* __restrict__ cnt,
        const int* __restrict__ list, float* __restrict__ vout) {
    int e = blockIdx.x;
    int o0 = blockIdx.y * 16;
    __shared__ char wqs[16 * 2048];
    __shared__ float xs[2048];
    int tid = threadIdx.x;
    const float* mbase = masks + (size_t)e * 1024 * 2048;
#pragma unroll
    for (int p = 0; p < 32; ++p) {
        int i = tid + p * 256;
        int o = i >> 9;
        int d = (i & 511) << 2;
        const float4 w4 = *(const float4*)(wv + (size_t)(o0 + o) * 2048 + d);
        const float4 m4 = *(const float4*)(mbase + (size_t)(o0 + o) * 2048 + d);
        char4 pk;
        pk.x = (char)(ternf(w4.x) * m4.x);
        pk.y = (char)(ternf(w4.y) * m4.y);
        pk.z = (char)(ternf(w4.z) * m4.z);
        pk.w = (char)(ternf(w4.w) * m4.w);
        *(char4*)&wqs[(size_t)o * 2048 + d] = pk;
    }
    int n = cnt[e];
    int lane = tid & 63, wave = tid >> 6;
    for (int j = 0; j < n; ++j) {
        int t = list[e * S_ + j];
        __syncthreads();
        for (int p = tid; p < 512; p += 256)
            *(float4*)&xs[p * 4] = *(const float4*)(xn + (size_t)t * 2048 + p * 4);
        __syncthreads();
        float gate = wtop[t];
#pragma unroll
        for (int i = 0; i < 4; ++i) {
            int o = wave * 4 + i;
            float s = 0.f;
#pragma unroll
            for (int it = 0; it < 8; ++it) {
                int d = it * 256 + lane * 4;
                char4 pk = *(const char4*)&wqs[o * 2048 + d];
                float4 xv = *(const float4*)&xs[d];
                s += xv.x * (float)pk.x + xv.y * (float)pk.y +
                     xv.z * (float)pk.z + xv.w * (float)pk.w;
            }
            for (int off = 32; off > 0; off >>= 1) s += __shfl_down(s, off);
            if (lane == 0) {
                int oo = o0 + o;
                int kvh = oo >> 6, dd = oo & 63;
                vout[((size_t)kvh * S_ + t) * 64 + dd] = gate * sv[oo] * s;
            }
        }
    }
}

// ---------------- RoPE + transpose ----------------
__global__ void rope_kernel(const float* __restrict__ inp, float* __restrict__ outp, int nheads) {
    int i = blockIdx.x * 256 + threadIdx.x;
    int p = i & 31;
    int s = (i >> 5) & 1023;
    int h = i >> 15;
    if (h >= nheads) return;
    int stride = nheads * 64;
    const float* irow = inp + (size_t)s * stride + h * 64;
    float x1 = irow[p], x2 = irow[32 + p];
    float fr = expf(-(float)p * 0.28782313662425575f);
    float ang = (float)s * fr;
    float sn, cs;
    sincosf(ang, &sn, &cs);
    float* orow = outp + ((size_t)h * S_ + s) * 64;
    orow[p]      = x1 * cs + x2 * sn;
    orow[32 + p] = -x1 * sn + x2 * cs;
}

// ---------------- MFMA flash attention ----------------
__global__ __launch_bounds__(256) void attn3_kernel(
        const float* __restrict__ q, const float* __restrict__ k,
        const float* __restrict__ v, float* __restrict__ o) {
    int h = blockIdx.x;
    int qt = gridDim.y - 1 - blockIdx.y;   // heavy blocks first
    int kvh = h >> 1;
    const float* kb = k + (size_t)kvh * S_ * 64;
    const float* vb = v + (size_t)kvh * S_ * 64;
    __shared__ unsigned short Khi[64 * 72];
    __shared__ unsigned short Klo[64 * 72];
    __shared__ unsigned short Vt[64 * 72];     // Vt[dim][key]
    __shared__ unsigned short Ps[4][16 * 72];  // per-wave P tile
    int tid = threadIdx.x;
    int lane = tid & 63, wave = tid >> 6;
    int lm = lane & 15, lg = lane >> 4;

    bf16x8 qhi[2], qlo[2];
    {
        int qrow = qt * 64 + wave * 16 + lm;
        const float* qp = q + ((size_t)h * S_ + qrow) * 64;
#pragma unroll
        for (int c = 0; c < 2; ++c) {
            float4 v0 = *(const float4*)&qp[c * 32 + lg * 8];
            float4 v1 = *(const float4*)&qp[c * 32 + lg * 8 + 4];
            union { bf16x8 b; uint2 u[2]; } uh, ul;
            split4(v0, uh.u[0], ul.u[0]);
            split4(v1, uh.u[1], ul.u[1]);
            qhi[c] = uh.b; qlo[c] = ul.b;
        }
    }
    f32x4 oacc[4];
#pragma unroll
    for (int n = 0; n < 4; ++n) { f32x4 z = {0.f, 0.f, 0.f, 0.f}; oacc[n] = z; }
    float mrun[4], lrun[4];
#pragma unroll
    for (int r = 0; r < 4; ++r) { mrun[r] = -1e30f; lrun[r] = 0.f; }

    int ntile = qt + 1;
    for (int kt = 0; kt < ntile; ++kt) {
        int j0 = kt * 64;
        __syncthreads();
        {
            int key = lane, dg = wave;
            const float* kr = kb + (size_t)(j0 + key) * 64 + dg * 16;
            const float* vr = vb + (size_t)(j0 + key) * 64 + dg * 16;
            float4 k0 = ((const float4*)kr)[0], k1 = ((const float4*)kr)[1];
            float4 k2 = ((const float4*)kr)[2], k3 = ((const float4*)kr)[3];
            union { uint4 u; uint2 d[2]; } H0, H1, L0, L1;
            split4(k0, H0.d[0], L0.d[0]); split4(k1, H0.d[1], L0.d[1]);
            split4(k2, H1.d[0], L1.d[0]); split4(k3, H1.d[1], L1.d[1]);
            *(uint4*)&Khi[key * 72 + dg * 16]     = H0.u;
            *(uint4*)&Khi[key * 72 + dg * 16 + 8] = H1.u;
            *(uint4*)&Klo[key * 72 + dg * 16]     = L0.u;
            *(uint4*)&Klo[key * 72 + dg * 16 + 8] = L1.u;
            float vl[16];
            *(float4*)&vl[0]  = ((const float4*)vr)[0];
            *(float4*)&vl[4]  = ((const float4*)vr)[1];
            *(float4*)&vl[8]  = ((const float4*)vr)[2];
            *(float4*)&vl[12] = ((const float4*)vr)[3];
#pragma unroll
            for (int i = 0; i < 16; ++i)
                Vt[(dg * 16 + i) * 72 + key] = bf1(vl[i]);
        }
        __syncthreads();

        f32x4 sv[4];
#pragma unroll
        for (int n = 0; n < 4; ++n) {
            f32x4 s = {0.f, 0.f, 0.f, 0.f};
#pragma unroll
            for (int c = 0; c < 2; ++c) {
                int off = (n * 16 + lm) * 72 + c * 32 + lg * 8;
                bf16x8 bkh = *(const bf16x8*)&Khi[off];
                bf16x8 bkl = *(const bf16x8*)&Klo[off];
                s = __builtin_amdgcn_mfma_f32_16x16x32_bf16(qlo[c], bkh, s, 0, 0, 0);
                s = __builtin_amdgcn_mfma_f32_16x16x32_bf16(qhi[c], bkl, s, 0, 0, 0);
                s = __builtin_amdgcn_mfma_f32_16x16x32_bf16(qhi[c], bkh, s, 0, 0, 0);
            }
            sv[n] = s;
        }
#pragma unroll
        for (int n = 0; n < 4; ++n) {
            int kglob = j0 + n * 16 + lm;
#pragma unroll
            for (int r = 0; r < 4; ++r) {
                float s = sv[n][r] * 0.125f;
                if (kt == qt) {
                    int qrow_r = qt * 64 + wave * 16 + lg * 4 + r;
                    if (kglob > qrow_r) s = -1e30f;
                }
                sv[n][r] = s;
            }
        }
        float rmax[4];
#pragma unroll
        for (int r = 0; r < 4; ++r) {
            float m = fmaxf(fmaxf(sv[0][r], sv[1][r]), fmaxf(sv[2][r], sv[3][r]));
#pragma unroll
            for (int off = 1; off < 16; off <<= 1)
                m = fmaxf(m, __shfl_xor(m, off));
            rmax[r] = m;
        }
        float alpha[4], rsum[4];
#pragma unroll
        for (int r = 0; r < 4; ++r) {
            float mnew = fmaxf(mrun[r], rmax[r]);
            alpha[r] = __expf(mrun[r] - mnew);
            mrun[r] = mnew;
            rsum[r] = 0.f;
        }
#pragma unroll
        for (int n = 0; n < 4; ++n)
#pragma unroll
            for (int r = 0; r < 4; ++r) {
                float p = __expf(sv[n][r] - mrun[r]);
                sv[n][r] = p;
                rsum[r] += p;
            }
#pragma unroll
        for (int r = 0; r < 4; ++r) {
#pragma unroll
            for (int off = 1; off < 16; off <<= 1)
                rsum[r] += __shfl_xor(rsum[r], off);
            lrun[r] = lrun[r] * alpha[r] + rsum[r];
        }
#pragma unroll
        for (int n = 0; n < 4; ++n)
#pragma unroll
            for (int r = 0; r < 4; ++r)
                oacc[n][r] *= alpha[r];
#pragma unroll
        for (int n = 0; n < 4; ++n)
#pragma unroll
            for (int r = 0; r < 4; ++r)
                Ps[wave][(lg * 4 + r) * 72 + n * 16 + lm] = bf1(sv[n][r]);
        bf16x8 ap[2];
#pragma unroll
        for (int c = 0; c < 2; ++c)
            ap[c] = *(const bf16x8*)&Ps[wave][lm * 72 + c * 32 + lg * 8];
#pragma unroll
        for (int n = 0; n < 4; ++n) {
#pragma unroll
            for (int c = 0; c < 2; ++c) {
                bf16x8 bv = *(const bf16x8*)&Vt[(n * 16 + lm) * 72 + c * 32 + lg * 8];
                oacc[n] = __builtin_amdgcn_mfma_f32_16x16x32_bf16(ap[c], bv, oacc[n], 0, 0, 0);
            }
        }
    }
    float inv[4];
#pragma unroll
    for (int r = 0; r < 4; ++r) inv[r] = 1.f / lrun[r];
#pragma unroll
    for (int n = 0; n < 4; ++n)
#pragma unroll
        for (int r = 0; r < 4; ++r) {
            int row = qt * 64 + wave * 16 + lg * 4 + r;
            o[(size_t)row * 2048 + h * 64 + n * 16 + lm] = oacc[n][r] * inv[r];
        }
}

// ---------------- launcher ----------------
extern "C" void kernel_launch(void* const* d_in, const int* in_sizes, int n_in,
                              void* d_out, int out_size, void* d_ws, size_t ws_size,
                              hipStream_t stream) {
    const float* x        = (const float*)d_in[0];
    const float* wq       = (const float*)d_in[1];
    const float* sq       = (const float*)d_in[2];
    const float* Aq       = (const float*)d_in[3];
    const float* Bq       = (const float*)d_in[4];
    const float* wk       = (const float*)d_in[5];
    const float* sk       = (const float*)d_in[6];
    const float* Ak       = (const float*)d_in[7];
    const float* Bk       = (const float*)d_in[8];
    const float* wv       = (const float*)d_in[9];
    const float* sv       = (const float*)d_in[10];
    const float* masks    = (const float*)d_in[11];
    const float* router_w = (const float*)d_in[12];
    const float* wo       = (const float*)d_in[13];
    const float* so       = (const float*)d_in[14];
    const float* Ao       = (const float*)d_in[15];
    const float* Bo       = (const float*)d_in[16];
    const float* w1       = (const float*)d_in[17];
    const float* s1       = (const float*)d_in[18];
    const float* A1       = (const float*)d_in[19];
    const float* B1       = (const float*)d_in[20];
    const float* w2       = (const float*)d_in[21];
    const float* s2       = (const float*)d_in[22];
    const float* A2       = (const float*)d_in[23];
    const float* B2       = (const float*)d_in[24];

    float* ws   = (float*)d_ws;
    float* out  = (float*)d_out;
    float* xn   = ws + OFF_XN;
    float* qf   = ws + OFF_QF;
    float* kf   = ws + OFF_KF;
    float* qh   = ws + OFF_QH;
    float* kh   = ws + OFF_KH;
    float* vbuf = ws + OFF_V;
    float* obuf = ws + OFF_O;
    float* h1   = ws + OFF_H1;
    float* mbuf = ws + OFF_M;
    float* mu   = ws + OFF_MU;
    float* tvec = ws + OFF_T;
    float* gq   = ws + OFF_GQ;
    float* gk   = ws + OFF_GK;
    float* go   = ws + OFF_GO;
    float* g1   = ws + OFF_G1;
    float* g2   = ws + OFF_G2;
    float* wtop = ws + OFF_WTOP;
    int*   cnt  = (int*)(ws + OFF_CNT);
    int*   list = (int*)(ws + OFF_LIST);

    unsigned short* bb  = (unsigned short*)(ws + FP32_FLOATS);
    unsigned short* wqb = bb + BOFF_WQ;
    unsigned short* wkb = bb + BOFF_WK;
    unsigned short* wob = bb + BOFF_WO;
    unsigned short* w1b = bb + BOFF_W1;
    unsigned short* w2b = bb + BOFF_W2;
    unsigned short* xnb = bb + BOFF_XN;
    unsigned short* ob  = bb + BOFF_OB;
    unsigned short* mb  = bb + BOFF_MB;

    const bool fast = ws_size >= WS_NEED;

    hipMemsetAsync(cnt, 0, E_ * sizeof(int), stream);

    if (fast) {
        ternb_kernel<<<(D_ * D_ / 4) / 256, 256, 0, stream>>>(wq, (unsigned*)wqb, D_ * D_ / 4);
        ternb_kernel<<<(1024 * D_ / 4) / 256, 256, 0, stream>>>(wk, (unsigned*)wkb, 1024 * D_ / 4);
        ternb_kernel<<<(D_ * D_ / 4) / 256, 256, 0, stream>>>(wo, (unsigned*)wob, D_ * D_ / 4);
        ternb_kernel<<<(FF_ * D_ / 4) / 256, 256, 0, stream>>>(w1, (unsigned*)w1b, FF_ * D_ / 4);
        ternb_kernel<<<(D_ * FF_ / 4) / 256, 256, 0, stream>>>(w2, (unsigned*)w2b, D_ * FF_ / 4);
    }

    rms_kernel<<<S_, 256, 0, stream>>>(x, xn, D_);
    colmean_kernel<<<D_ / 64, 256, 0, stream>>>(xn, mu, S_, D_);
    if (fast) cvtb_kernel<<<(S_ * D_ / 4) / 256, 256, 0, stream>>>(xn, (unsigned*)xnb, S_ * D_ / 4);

    // Q projection (split-bf16: score path needs fp32-grade accuracy)
    bmu_kernel<<<R_, 256, 0, stream>>>(Bq, mu, tvec, D_);
    gate_kernel<<<D_ / 256, 256, 0, stream>>>(Aq, tvec, sq, gq, D_);
    if (fast) gemm_mfma_dbl<1><<<dim3(D_ / 128, S_ / 64), 256, 0, stream>>>(xn, wqb, gq, qf, S_, D_, D_);
    else      gemm_mfma_dbl<0><<<dim3(D_ / 128, S_ / 64), 256, 0, stream>>>(xn, wq, gq, qf, S_, D_, D_);

    // K projection (split-bf16)
    bmu_kernel<<<R_, 256, 0, stream>>>(Bk, mu, tvec, D_);
    gate_kernel<<<1024 / 256, 256, 0, stream>>>(Ak, tvec, sk, gk, 1024);
    if (fast) gemm_mfma_dbl<1><<<dim3(1024 / 128, S_ / 64), 256, 0, stream>>>(xn, wkb, gk, kf, S_, 1024, D_);
    else      gemm_mfma_dbl<0><<<dim3(1024 / 128, S_ / 64), 256, 0, stream>>>(xn, wk, gk, kf, S_, 1024, D_);

    // V (MoE)
    router_kernel<<<S_, 256, 0, stream>>>(xn, router_w, wtop, cnt, list);
    if (fast) moe_mfma_kernel<<<dim3(E_, 1024 / 16), 256, 0, stream>>>(xnb, wv, sv, masks, wtop, cnt, list, vbuf);
    else      moe_kernel<<<dim3(E_, 1024 / 16), 256, 0, stream>>>(xn, wv, sv, masks, wtop, cnt, list, vbuf);

    // RoPE + head transpose
    rope_kernel<<<(H_ * S_ * 32) / 256, 256, 0, stream>>>(qf, qh, H_);
    rope_kernel<<<(HKV_ * S_ * 32) / 256, 256, 0, stream>>>(kf, kh, HKV_);

    // attention (MFMA flash)
    attn3_kernel<<<dim3(H_, S_ / 64), 256, 0, stream>>>(qh, kh, vbuf, obuf);

    // output projection + residual (smooth path: single bf16)
    colmean_kernel<<<D_ / 64, 256, 0, stream>>>(obuf, mu, S_, D_);
    bmu_kernel<<<R_, 256, 0, stream>>>(Bo, mu, tvec, D_);
    gate_kernel<<<D_ / 256, 256, 0, stream>>>(Ao, tvec, so, go, D_);
    if (fast) {
        cvtb_kernel<<<(S_ * D_ / 4) / 256, 256, 0, stream>>>(obuf, (unsigned*)ob, S_ * D_ / 4);
        gemm_mfma<1, 1><<<dim3(D_ / 128, S_ / 64), 256, 0, stream>>>(ob, wob, go, x, h1, S_, D_, D_);
    } else {
        gemm_mfma<1, 0><<<dim3(D_ / 128, S_ / 64), 256, 0, stream>>>(obuf, wo, go, x, h1, S_, D_, D_);
    }

    // MLP up (relu^2)
    rms_kernel<<<S_, 256, 0, stream>>>(h1, xn, D_);
    colmean_kernel<<<D_ / 64, 256, 0, stream>>>(xn, mu, S_, D_);
    bmu_kernel<<<R_, 256, 0, stream>>>(B1, mu, tvec, D_);
    gate_kernel<<<FF_ / 256, 256, 0, stream>>>(A1, tvec, s1, g1, FF_);
    if (fast) {
        cvtb_kernel<<<(S_ * D_ / 4) / 256, 256, 0, stream>>>(xn, (unsigned*)xnb, S_ * D_ / 4);
        gemm_mfma<2, 1><<<dim3(FF_ / 128, S_ / 64), 256, 0, stream>>>(xnb, w1b, g1, nullptr, mbuf, S_, FF_, D_);
    } else {
        gemm_mfma<2, 0><<<dim3(FF_ / 128, S_ / 64), 256, 0, stream>>>(xn, w1, g1, nullptr, mbuf, S_, FF_, D_);
    }

    // MLP down + residual -> out
    colmean_kernel<<<FF_ / 64, 256, 0, stream>>>(mbuf, mu, S_, FF_);
    bmu_kernel<<<R_, 256, 0, stream>>>(B2, mu, tvec, FF_);
    gate_kernel<<<D_ / 256, 256, 0, stream>>>(A2, tvec, s2, g2, D_);
    if (fast) {
        cvtb_kernel<<<(S_ * FF_ / 4) / 256, 256, 0, stream>>>(mbuf, (unsigned*)mb, S_ * FF_ / 4);
        gemm_mfma<1, 1><<<dim3(D_ / 128, S_ / 64), 256, 0, stream>>>(mb, w2b, g2, h1, out, S_, D_, FF_);
    } else {
        gemm_mfma<1, 0><<<dim3(D_ / 128, S_ / 64), 256, 0, stream>>>(mbuf, w2, g2, h1, out, S_, D_, FF_);
    }
}